// Round 2
// baseline (8983.199 us; speedup 1.0000x reference)
//
#include <hip/hip_runtime.h>
#include <stdint.h>
#include <math.h>

typedef __attribute__((ext_vector_type(8))) short bf16x8;
typedef __attribute__((ext_vector_type(4))) float f32x4;
typedef __attribute__((ext_vector_type(4))) unsigned int u32x4;

#define BATCH 4
#define T_M 32
#define DE 128
#define T_W 2560
#define NWG 448       /* 448 blocks; 56 elected same-XCD workers, rest exit */
#define POLL_LIM 4096 /* local epoch-poll rounds before sticky fallback to LLC */

__device__ __forceinline__ float b2f(unsigned short h) {
  return __uint_as_float(((unsigned int)h) << 16);
}
__device__ __forceinline__ unsigned short f2b(float f) {
  unsigned int u = __float_as_uint(f);
  u = u + 0x7fffu + ((u >> 16) & 1u);   // RNE
  return (unsigned short)(u >> 16);
}
__device__ __forceinline__ float blo(unsigned int u){ return __uint_as_float(u << 16); }
__device__ __forceinline__ float bhi(unsigned int u){ return __uint_as_float(u & 0xffff0000u); }
__device__ __forceinline__ float sigm(float x){
  return __builtin_amdgcn_rcpf(1.f + __expf(-x));
}
__device__ __forceinline__ float tanh_fast(float x){
  float x2 = fminf(fmaxf(x + x, -30.f), 30.f);
  return 1.f - 2.f * __builtin_amdgcn_rcpf(__expf(x2) + 1.f);
}
__device__ __forceinline__ float gelu_exact(float x){ return 0.5f * x * (1.f + erff(x * 0.70710678118654752f)); }

// ---------------- fused preprocessing: 4 bf16 casts + Whh swizzle ----------------
__global__ __launch_bounds__(256) void k_prep(
    const float* __restrict__ wih, const float* __restrict__ wp,
    const float* __restrict__ wd, const float* __restrict__ e,
    const float* __restrict__ whh,
    unsigned short* __restrict__ wih_b, unsigned short* __restrict__ wp_b,
    unsigned short* __restrict__ wd_b, unsigned short* __restrict__ eb,
    unsigned short* __restrict__ whh_p)
{
  int idx = blockIdx.x * 256 + threadIdx.x;
  const int N0 = 2688 * 512, N1 = 512 * 896, N2 = 256 * 512, N3 = 256 * 256;
  if (idx < N0) { wih_b[idx] = f2b(wih[idx]); return; }
  idx -= N0;
  if (idx < N1) { wp_b[idx] = f2b(wp[idx]); return; }
  idx -= N1;
  if (idx < N2) { wd_b[idx] = f2b(wd[idx]); return; }
  idx -= N2;
  if (idx < N3) { eb[idx] = f2b(e[idx]); return; }
  idx -= N3;
  if (idx >= 224 * 28 * 512) return;
  int j    = idx & 7;
  int r16  = (idx >> 3) & 15;
  int quad = (idx >> 7) & 3;
  int kc   = (idx >> 9) % 28;
  int G    = (idx >> 9) / 28;
  unsigned short val = 0;
  if (r16 < 12) {
    int row = (r16 >> 2) * 896 + G * 4 + (r16 & 3);
    int col = kc * 32 + quad * 8 + j;
    val = f2b(whh[(size_t)row * 896 + col]);
  }
  whh_p[idx] = val;
}

// ---------------- encoder: input projections gi = in @ Wih^T + bih (float4) ---------
__global__ __launch_bounds__(384) void k_gi_enc(
    const float* __restrict__ in, const float* __restrict__ Wih,
    const float* __restrict__ bih, float* __restrict__ out, int K)
{
  __shared__ float in_s[256];
  int tb = blockIdx.x;
  for (int i = threadIdx.x; i < K; i += 384) in_s[i] = in[tb * K + i];
  __syncthreads();
  int row = threadIdx.x;
  float acc = bih[row];
  const float* wr = Wih + row * K;
  for (int k = 0; k < K; k += 4) {
    float4 w = *(const float4*)(wr + k);
    float4 v = *(const float4*)(in_s + k);
    acc += w.x * v.x + w.y * v.y + w.z * v.z + w.w * v.w;
  }
  out[tb * 384 + row] = acc;
}

// ---------------- encoder: sequential scan, one WG per direction ----------------
// Phase 1: one thread per Whh row (384), computes all 4 batches (no redundant
// Whh re-reads). FP accumulation order per (row,b) identical to baseline.
__global__ __launch_bounds__(512) void k_scan_enc(
    const float* __restrict__ gi_f, const float* __restrict__ gi_b,
    const float* __restrict__ whh_f, const float* __restrict__ bhh_f,
    const float* __restrict__ whh_b, const float* __restrict__ bhh_b,
    float* __restrict__ c_out, unsigned short* __restrict__ cb)   // (32,4,256)
{
  const int dir = blockIdx.x, tid = threadIdx.x;
  const float* gi  = dir ? gi_b  : gi_f;
  const float* whh = dir ? whh_b : whh_f;
  const float* bhh = dir ? bhh_b : bhh_f;
  __shared__ unsigned short h_s[BATCH][DE + 8];
  __shared__ float gh_s[384][4];
  __shared__ float bhh_s[384];
  for (int i = tid; i < 384; i += 512) bhh_s[i] = bhh[i];
  for (int i = tid; i < BATCH * (DE + 8); i += 512) ((unsigned short*)h_s)[i] = 0;
  __syncthreads();
  for (int s = 0; s < T_M; ++s) {
    int t = dir ? (T_M - 1 - s) : s;
    if (tid < 384) {
      const float* wr = whh + tid * DE;
      float a0 = 0.f, a1 = 0.f, a2 = 0.f, a3 = 0.f;
      for (int j = 0; j < DE; j += 8) {
        float4 w0 = *(const float4*)(wr + j);
        float4 w1 = *(const float4*)(wr + j + 4);
        uint4 h0 = *(const uint4*)&h_s[0][j];
        uint4 h1 = *(const uint4*)&h_s[1][j];
        uint4 h2 = *(const uint4*)&h_s[2][j];
        uint4 h3 = *(const uint4*)&h_s[3][j];
        a0 += w0.x * blo(h0.x) + w0.y * bhi(h0.x) + w0.z * blo(h0.y) + w0.w * bhi(h0.y);
        a0 += w1.x * blo(h0.z) + w1.y * bhi(h0.z) + w1.z * blo(h0.w) + w1.w * bhi(h0.w);
        a1 += w0.x * blo(h1.x) + w0.y * bhi(h1.x) + w0.z * blo(h1.y) + w0.w * bhi(h1.y);
        a1 += w1.x * blo(h1.z) + w1.y * bhi(h1.z) + w1.z * blo(h1.w) + w1.w * bhi(h1.w);
        a2 += w0.x * blo(h2.x) + w0.y * bhi(h2.x) + w0.z * blo(h2.y) + w0.w * bhi(h2.y);
        a2 += w1.x * blo(h2.z) + w1.y * bhi(h2.z) + w1.z * blo(h2.w) + w1.w * bhi(h2.w);
        a3 += w0.x * blo(h3.x) + w0.y * bhi(h3.x) + w0.z * blo(h3.y) + w0.w * bhi(h3.y);
        a3 += w1.x * blo(h3.z) + w1.y * bhi(h3.z) + w1.z * blo(h3.w) + w1.w * bhi(h3.w);
      }
      float bb_ = bhh_s[tid];
      *(float4*)&gh_s[tid][0] = make_float4(a0 + bb_, a1 + bb_, a2 + bb_, a3 + bb_);
    }
    __syncthreads();
    {
      int u = tid >> 2, b = tid & 3;
      const float* git = gi + (t * BATCH + b) * 384;
      float r = sigm(git[u] + gh_s[u][b]);
      float z = sigm(git[DE + u] + gh_s[DE + u][b]);
      float n = tanh_fast(git[2 * DE + u] + r * gh_s[2 * DE + u][b]);
      float hold = b2f(h_s[b][u]);
      float hnew = (1.f - z) * n + z * hold;
      int oi = (t * BATCH + b) * 256 + dir * DE + u;
      c_out[oi] = hnew;
      if (cb) cb[oi] = f2b(hnew);
      h_s[b][u] = f2b(hnew);
    }
    __syncthreads();
  }
}

// ---------------- MFMA GEMM: C(MxN) = act(A(bf16 MxK) @ B(bf16 NxK)^T + bias) -------
__global__ __launch_bounds__(256) void k_mgemm(
    const unsigned short* __restrict__ A, const unsigned short* __restrict__ B,
    const float* __restrict__ bias, void* __restrict__ C,
    int M, int N, int K, int act, int c_bf16, int swz, int afuse,
    const unsigned short* __restrict__ Eb, const unsigned short* __restrict__ c1b,
    const float* __restrict__ yw)
{
  __shared__ unsigned short As[128][40];
  __shared__ unsigned short Bs[128][40];
  const int tid = threadIdx.x;
  const int m0 = blockIdx.x * 128, n0 = blockIdx.y * 128;
  const int lane = tid & 63, wave = tid >> 6;
  const int wy = wave >> 1, wx = wave & 1;
  const int row16 = lane & 15, quad = lane >> 4;
  const int sr = tid >> 1, sc = (tid & 1) * 16;
  const unsigned short* arow0 = nullptr;
  const unsigned short* arow1 = nullptr;
  if (afuse) {
    int row = m0 + sr, tt = row >> 2, b = row & 3;
    float w = (tt == 0) ? 0.f : yw[(tt - 1) * 4 + b];
    int q = (int)floorf((w + 1.f) * 128.f);
    q = q < 0 ? 0 : (q > 255 ? 255 : q);
    arow0 = Eb + q * 256;
    arow1 = c1b + ((tt / 80) * 4 + b) * 256;
  }
  f32x4 acc[4][4] = {};
  for (int kt = 0; kt < K; kt += 32) {
    uint4 av, av2;
    if (afuse) {
      int kk = kt + sc;
      const unsigned short* src = (kk < 256) ? (arow0 + kk) : (arow1 + kk - 256);
      av  = *(const uint4*)src;
      av2 = *(const uint4*)(src + 8);
    } else {
      av  = *(const uint4*)(A + (size_t)(m0 + sr) * K + kt + sc);
      av2 = *(const uint4*)(A + (size_t)(m0 + sr) * K + kt + sc + 8);
    }
    uint4 bv  = *(const uint4*)(B + (size_t)(n0 + sr) * K + kt + sc);
    uint4 bv2 = *(const uint4*)(B + (size_t)(n0 + sr) * K + kt + sc + 8);
    __syncthreads();
    *(uint4*)&As[sr][sc] = av; *(uint4*)&As[sr][sc + 8] = av2;
    *(uint4*)&Bs[sr][sc] = bv; *(uint4*)&Bs[sr][sc + 8] = bv2;
    __syncthreads();
    bf16x8 af[4], bf[4];
    #pragma unroll
    for (int i = 0; i < 4; ++i) af[i] = *(const bf16x8*)&As[wy * 64 + i * 16 + row16][quad * 8];
    #pragma unroll
    for (int j = 0; j < 4; ++j) bf[j] = *(const bf16x8*)&Bs[wx * 64 + j * 16 + row16][quad * 8];
    #pragma unroll
    for (int i = 0; i < 4; ++i)
      #pragma unroll
      for (int j = 0; j < 4; ++j)
        acc[i][j] = __builtin_amdgcn_mfma_f32_16x16x32_bf16(af[i], bf[j], acc[i][j], 0, 0, 0);
  }
  #pragma unroll
  for (int i = 0; i < 4; ++i) {
    #pragma unroll
    for (int j = 0; j < 4; ++j) {
      int col = n0 + wx * 64 + j * 16 + row16;
      float bs = bias[col];
      #pragma unroll
      for (int r = 0; r < 4; ++r) {
        int row = m0 + wy * 64 + i * 16 + quad * 4 + r;
        float v = acc[i][j][r] + bs;
        if (act) v = gelu_exact(v);
        if (swz) {
          int t = row >> 2, b = row & 3;
          int g = col / 896, rem = col - g * 896;
          int G = rem >> 2, u = rem & 3;
          ((unsigned short*)C)[(size_t)(t * 224 + G) * 48 + g * 16 + b * 4 + u] = f2b(v);
        } else if (c_bf16) {
          ((unsigned short*)C)[(size_t)row * N + col] = f2b(v);
        } else {
          ((float*)C)[(size_t)row * N + col] = v;
        }
      }
    }
  }
}

// ---------------- wav GRU: elected single-XCD group, epoch protocol -----------------
// 448 blocks launched; each reads its real XCD (HW_REG_XCC_ID), registers on a
// per-XCD arrival counter; first XCD to collect 56 blocks wins (CAS). Winner's
// ranks 0..55 are the workers (all provably same XCD); everyone else exits.
// Timeout CAS forces mode 15 = device-scope baseline protocol (bid<56 work).
//
// Step protocol (fast): publishers store 8B h-data (sc0, XCD L2) + 16B tagged
// mirror (sc0 sc1, LLC), vmcnt(1) [waits local ACK only], then bump a per-wave
// epoch dword (sc0). Readers poll the 224 epoch dwords (1 dwordx4/lane), then
// read the 7KB state ONCE as 16B chunks. Sticky per-wave fallback to tagged
// LLC polling if the local path stalls POLL_LIM rounds.
__global__ __launch_bounds__(256, 2) void k_wav_rnn(
    const unsigned short* __restrict__ whh_p,  // swizzled (224,28,4,16,8) bf16
    const float* __restrict__ bhh,             // (2688,)
    const unsigned short* __restrict__ gp_,    // packed gi (2560,224,3,4,4) bf16
    int* __restrict__ ctl,                     // [16] zeroed: 0..7 arrivals, 8 winner
    unsigned short* __restrict__ hLd,          // [2][4][896] bf16 local data (zeroed)
    int* __restrict__ hLe,                     // [224] epochs (zeroed)
    unsigned int* __restrict__ hG,             // [2][4*224] 16B tagged pkts (zeroed)
    unsigned int* __restrict__ O32)            // (10240,448) dwords of bf16 pairs
{
  const int tid = threadIdx.x;
  const int lane = tid & 63, wave = tid >> 6;

  __shared__ int s_wg, s_mode;

  // ---- election ----
  int xcc;
  asm volatile("s_getreg_b32 %0, hwreg(HW_REG_XCC_ID)" : "=s"(xcc));
  xcc &= 7;
  if (tid == 0) {
    int rank = atomicAdd(&ctl[xcc], 1);
    if (rank == 55) atomicCAS(&ctl[8], 0, xcc + 1);
    int w, tries = 0;
    for (;;) {
      asm volatile("global_load_dword %0, %1, off sc0 sc1\ns_waitcnt vmcnt(0)"
                   : "=v"(w) : "v"((unsigned long long)&ctl[8]) : "memory");
      if (w) break;
      if (++tries > 20000) atomicCAS(&ctl[8], 0, 15);
    }
    if (w == 15) { s_mode = 1; s_wg = blockIdx.x; }
    else         { s_mode = 0; s_wg = (xcc == w - 1) ? rank : 999; }
  }
  __syncthreads();
  const int fmode = s_mode;
  const int wg = s_wg;
  if (wg >= 56) return;

  const int G = wg * 4 + wave;

  __shared__ unsigned short h_lds[2][4][912];  // h(t) double buffer, stride 1824B
  __shared__ float phh[4][3][4][4];            // [wave][gate][batch][unit]

  const int r16 = lane & 15, quad = lane >> 4, bb = lane & 3;
  const int fu = (lane >> 2) & 3, fb = lane & 3;

  // ---- Whh fragments -> VGPRs (28 x bf16x8 = 112 regs) ----
  bf16x8 wf[28];
  {
    const bf16x8* W8 = (const bf16x8*)whh_p + (size_t)G * 28 * 64;
    #pragma unroll
    for (int kc = 0; kc < 28; ++kc)
      wf[kc] = W8[(kc * 4 + quad) * 16 + r16];
  }

  // ---- per-lane bias + recurrent state ----
  const float br_ = bhh[G * 4 + fu];
  const float bz_ = bhh[896 + G * 4 + fu];
  const float bn_ = bhh[1792 + G * 4 + fu];
  float hprev = 0.f;
  const unsigned short* gl0 = gp_ + (size_t)G * 48 + fb * 4 + fu;
  unsigned short cr = gl0[0], cz = gl0[16], cn = gl0[32];   // gi(0), raw bf16 bits

  // ---- chunk responsibility: thread tid<224 owns 16B chunks tid and tid+224 ----
  const int hasC = (tid < 224);
  const int c0 = hasC ? tid : 0;
  const int c1 = hasC ? tid + 224 : 0;
  const int b0 = c0 / 112, k0 = c0 % 112;
  const int b1 = c1 / 112, k1 = c1 % 112;

  const unsigned long long ldB = (unsigned long long)hLd;
  const unsigned long long geB = (unsigned long long)hLe;
  const unsigned long long gB  = (unsigned long long)hG;
  const unsigned long long aE  = geB + (unsigned long long)((lane < 56 ? lane : 55) * 16);

  int use_glob = fmode;

  for (int t = 0; t < T_W; ++t) {
    const int par = t & 1;

    // ---- acquire h(t) ----
    if (!use_glob) {
      int tries = 0;
      for (;;) {
        u32x4 e;
        asm volatile("global_load_dwordx4 %0, %1, off sc0\ns_waitcnt vmcnt(0)"
                     : "=&v"(e) : "v"(aE) : "memory");
        int ok = ((int)e.x >= t) && ((int)e.y >= t) && ((int)e.z >= t) && ((int)e.w >= t);
        if (__all(ok)) break;
        if (++tries > POLL_LIM) { use_glob = 1; break; }
      }
    }
    if (!use_glob) {
      if (hasC) {
        u32x4 d0, d1;
        unsigned long long aD0 = ldB + (unsigned long long)(par * 7168 + b0 * 1792 + k0 * 16);
        unsigned long long aD1 = ldB + (unsigned long long)(par * 7168 + b1 * 1792 + k1 * 16);
        asm volatile("global_load_dwordx4 %0, %2, off sc0\n"
                     "global_load_dwordx4 %1, %3, off sc0\n"
                     "s_waitcnt vmcnt(0)"
                     : "=&v"(d0), "=&v"(d1) : "v"(aD0), "v"(aD1) : "memory");
        *(u32x4*)((char*)h_lds + par * 7296 + b0 * 1824 + k0 * 16) = d0;
        *(u32x4*)((char*)h_lds + par * 7296 + b1 * 1824 + k1 * 16) = d1;
      }
    } else {
      if (hasC) {
        unsigned long long aG0 = gB + (unsigned long long)((par * 896 + b0 * 224 + 2 * k0) * 16);
        unsigned long long aG2 = gB + (unsigned long long)((par * 896 + b1 * 224 + 2 * k1) * 16);
        u32x4 g0, g1, g2, g3;
        const unsigned int tg = (unsigned int)t;
        for (;;) {
          asm volatile("global_load_dwordx4 %0, %4, off sc0 sc1\n"
                       "global_load_dwordx4 %1, %5, off sc0 sc1\n"
                       "global_load_dwordx4 %2, %6, off sc0 sc1\n"
                       "global_load_dwordx4 %3, %7, off sc0 sc1\n"
                       "s_waitcnt vmcnt(0)"
                       : "=&v"(g0), "=&v"(g1), "=&v"(g2), "=&v"(g3)
                       : "v"(aG0), "v"(aG0 + 16), "v"(aG2), "v"(aG2 + 16)
                       : "memory");
          unsigned int bad = (g0.z ^ tg) | (g1.z ^ tg) | (g2.z ^ tg) | (g3.z ^ tg);
          if (!__any(bad != 0)) break;
        }
        u32x4 d0, d1;
        d0.x = g0.x; d0.y = g0.y; d0.z = g1.x; d0.w = g1.y;
        d1.x = g2.x; d1.y = g2.y; d1.z = g3.x; d1.w = g3.y;
        *(u32x4*)((char*)h_lds + par * 7296 + b0 * 1824 + k0 * 16) = d0;
        *(u32x4*)((char*)h_lds + par * 7296 + b1 * 1824 + k1 * 16) = d1;
      }
    }

    // ---- issue gi(t+1) loads now (consumed at next finalize) ----
    int tn = (t + 1 < T_W) ? (t + 1) : t;
    const unsigned short* gp = gp_ + (size_t)tn * 10752 + G * 48 + fb * 4 + fu;
    unsigned short nr_ = gp[0], nz_ = gp[16], nn_ = gp[32];

    __syncthreads();   // h(t) fully in LDS

    // ---- 28 MFMAs, 4 interleaved accumulator chains ----
    f32x4 ac0 = {}, ac1 = {}, ac2 = {}, ac3 = {};
    #pragma unroll
    for (int kc = 0; kc < 28; kc += 4) {
      bf16x8 h0 = *(const bf16x8*)&h_lds[par][bb][(kc + 0) * 32 + quad * 8];
      bf16x8 h1 = *(const bf16x8*)&h_lds[par][bb][(kc + 1) * 32 + quad * 8];
      bf16x8 h2 = *(const bf16x8*)&h_lds[par][bb][(kc + 2) * 32 + quad * 8];
      bf16x8 h3 = *(const bf16x8*)&h_lds[par][bb][(kc + 3) * 32 + quad * 8];
      ac0 = __builtin_amdgcn_mfma_f32_16x16x32_bf16(wf[kc + 0], h0, ac0, 0, 0, 0);
      ac1 = __builtin_amdgcn_mfma_f32_16x16x32_bf16(wf[kc + 1], h1, ac1, 0, 0, 0);
      ac2 = __builtin_amdgcn_mfma_f32_16x16x32_bf16(wf[kc + 2], h2, ac2, 0, 0, 0);
      ac3 = __builtin_amdgcn_mfma_f32_16x16x32_bf16(wf[kc + 3], h3, ac3, 0, 0, 0);
    }
    f32x4 ac;
    ac[0] = ac0[0] + ac1[0] + ac2[0] + ac3[0];
    ac[1] = ac0[1] + ac1[1] + ac2[1] + ac3[1];
    ac[2] = ac0[2] + ac1[2] + ac2[2] + ac3[2];
    ac[3] = ac0[3] + ac1[3] + ac2[3] + ac3[3];

    // ---- in-wave transpose via LDS ----
    if (r16 < 4 && quad < 3)
      *(f32x4*)&phh[wave][quad][r16][0] = ac;
    asm volatile("s_waitcnt lgkmcnt(0)" ::: "memory");   // same-wave DS in-order

    // ---- finalize my 16 h values (lanes 0-15; others duplicate harmlessly) ----
    float pr = phh[wave][0][fb][fu];
    float pz = phh[wave][1][fb][fu];
    float pn = phh[wave][2][fb][fu];
    float r = sigm(b2f(cr) + br_ + pr);
    float z = sigm(b2f(cz) + bz_ + pz);
    float n = tanh_fast(b2f(cn) + bn_ + r * pn);
    float h = (1.f - z) * n + z * hprev;
    hprev = h;
    unsigned int hu = f2b(h);
    cr = nr_; cz = nz_; cn = nn_;

    // ---- publish: lanes 0-3 own packet (batch b = lane) ----
    int b = lane & 3;
    unsigned int u0v = (unsigned int)__shfl((int)hu, 0 + b);
    unsigned int u1v = (unsigned int)__shfl((int)hu, 4 + b);
    unsigned int u2v = (unsigned int)__shfl((int)hu, 8 + b);
    unsigned int u3v = (unsigned int)__shfl((int)hu, 12 + b);
    if (lane < 4) {
      unsigned int lo = (u0v & 0xffffu) | (u1v << 16);
      unsigned int hi = (u2v & 0xffffu) | (u3v << 16);
      const int pn2 = (t + 1) & 1;
      // O32 output (plain store, oldest in-flight)
      *(uint2*)(O32 + (size_t)(t * 4 + b) * 448 + G * 2) = make_uint2(lo, hi);
      if (!fmode) {
        unsigned long long aL = ldB + (unsigned long long)(pn2 * 7168 + b * 1792 + G * 8);
        uint2 ld2 = make_uint2(lo, hi);
        asm volatile("global_store_dwordx2 %0, %1, off sc0" :: "v"(aL), "v"(ld2) : "memory");
      }
      u32x4 pkt;
      pkt.x = lo; pkt.y = hi; pkt.z = (unsigned int)(t + 1); pkt.w = 0u;
      unsigned long long aGp = gB + (unsigned long long)((pn2 * 896 + b * 224 + G) * 16);
      asm volatile("global_store_dwordx4 %0, %1, off sc0 sc1" :: "v"(aGp), "v"(pkt) : "memory");
      if (!fmode) {
        // wait for all but the newest (the LLC mirror) -> local pkt ACKed in L2
        asm volatile("s_waitcnt vmcnt(1)" ::: "memory");
        if (lane == 0) {
          unsigned long long aEp = geB + (unsigned long long)((wg * 4 + wave) * 4);
          int ev = t + 1;
          asm volatile("global_store_dword %0, %1, off sc0" :: "v"(aEp), "v"(ev) : "memory");
        }
      }
    }
  }
}

// ---------------- NLL: per-block reduction, NO atomics ----------------
__global__ __launch_bounds__(256) void k_nll(
    const float* __restrict__ logits, const float* __restrict__ y,
    float* __restrict__ partials)
{
  __shared__ float ps[4];
  int wid = threadIdx.x >> 6, lane = threadIdx.x & 63;
  int row = blockIdx.x * 4 + wid;
  const float* lr = logits + (size_t)row * 256;
  float v0 = lr[lane], v1 = lr[lane + 64], v2 = lr[lane + 128], v3 = lr[lane + 192];
  float mx = fmaxf(fmaxf(v0, v1), fmaxf(v2, v3));
  for (int off = 32; off > 0; off >>= 1) mx = fmaxf(mx, __shfl_xor(mx, off));
  float se = __expf(v0 - mx) + __expf(v1 - mx) + __expf(v2 - mx) + __expf(v3 - mx);
  for (int off = 32; off > 0; off >>= 1) se += __shfl_xor(se, off);
  if (lane == 0) {
    float w = y[row];
    int q = (int)floorf((w + 1.f) * 128.f);
    q = q < 0 ? 0 : (q > 255 ? 255 : q);
    ps[wid] = (logf(se) + mx) - lr[q];
  }
  __syncthreads();
  if (threadIdx.x == 0) partials[blockIdx.x] = ps[0] + ps[1] + ps[2] + ps[3];
}

__global__ __launch_bounds__(256) void k_final(const float* __restrict__ partials,
                                               float* __restrict__ out)
{
  __shared__ float s[4];
  int tid = threadIdx.x;
  float a = 0.f;
  for (int i = tid; i < 2560; i += 256) a += partials[i];
  for (int off = 32; off > 0; off >>= 1) a += __shfl_xor(a, off);
  if ((tid & 63) == 0) s[tid >> 6] = a;
  __syncthreads();
  if (tid == 0) out[0] = (s[0] + s[1] + s[2] + s[3]) * (1.f / 10240.f);
}

// ---------------- host ----------------
extern "C" void kernel_launch(void* const* d_in, const int* in_sizes, int n_in,
                              void* d_out, int out_size, void* d_ws, size_t ws_size,
                              hipStream_t stream)
{
  const float* x       = (const float*)d_in[0];
  const float* y       = (const float*)d_in[1];
  const float* m0f_Wih = (const float*)d_in[2];
  const float* m0f_Whh = (const float*)d_in[3];
  const float* m0f_bih = (const float*)d_in[4];
  const float* m0f_bhh = (const float*)d_in[5];
  const float* m0b_Wih = (const float*)d_in[6];
  const float* m0b_Whh = (const float*)d_in[7];
  const float* m0b_bih = (const float*)d_in[8];
  const float* m0b_bhh = (const float*)d_in[9];
  const float* m1f_Wih = (const float*)d_in[10];
  const float* m1f_Whh = (const float*)d_in[11];
  const float* m1f_bih = (const float*)d_in[12];
  const float* m1f_bhh = (const float*)d_in[13];
  const float* m1b_Wih = (const float*)d_in[14];
  const float* m1b_Whh = (const float*)d_in[15];
  const float* m1b_bih = (const float*)d_in[16];
  const float* m1b_bhh = (const float*)d_in[17];
  const float* w_Wih   = (const float*)d_in[18];
  const float* w_Whh   = (const float*)d_in[19];
  const float* w_bih   = (const float*)d_in[20];
  const float* w_bhh   = (const float*)d_in[21];
  const float* Wp      = (const float*)d_in[22];
  const float* bp      = (const float*)d_in[23];
  const float* E       = (const float*)d_in[24];
  const float* Wd      = (const float*)d_in[25];
  const float* bd      = (const float*)d_in[26];

  char* ws = (char*)d_ws;
  size_t off = 0;
  auto alloc = [&](size_t bytes) -> void* {
    void* p = ws + off;
    off += (bytes + 255) & ~(size_t)255;
    return p;
  };
  // misc (zeroed each launch): election ctl + packet/epoch buffers
  int*            ctl  = (int*)alloc(16 * 4);
  unsigned short* hLd  = (unsigned short*)alloc((size_t)2 * 4 * 896 * 2);   // 14336B
  int*            hLe  = (int*)alloc((size_t)224 * 4);                       // 896B
  unsigned int*   hG   = (unsigned int*)alloc((size_t)2 * 896 * 16);        // 28672B
  size_t misc_bytes = off;

  float* c0   = (float*)alloc((size_t)32 * 4 * 256 * 4);
  float* c1   = (float*)alloc((size_t)32 * 4 * 256 * 4);
  float* gi0f = (float*)alloc((size_t)32 * 4 * 384 * 4);
  float* gi0b = (float*)alloc((size_t)32 * 4 * 384 * 4);
  float* gi1f = (float*)alloc((size_t)32 * 4 * 384 * 4);
  float* gi1b = (float*)alloc((size_t)32 * 4 * 384 * 4);
  unsigned short* Eb    = (unsigned short*)alloc((size_t)256 * 256 * 2);
  unsigned short* c1b   = (unsigned short*)alloc((size_t)32 * 4 * 256 * 2);
  unsigned short* gpack = (unsigned short*)alloc((size_t)2560 * 224 * 48 * 2);
  unsigned int*   O32   = (unsigned int*)alloc((size_t)10240 * 448 * 4);
  unsigned short* O2    = (unsigned short*)alloc((size_t)10240 * 512 * 2);
  float*          LG    = (float*)alloc((size_t)10240 * 256 * 4);
  float*          PT    = (float*)alloc((size_t)2560 * 4);
  unsigned short* Wih_b = (unsigned short*)alloc((size_t)2688 * 512 * 2);
  unsigned short* Whh_p = (unsigned short*)alloc((size_t)224 * 28 * 512 * 2);
  unsigned short* Wp_b  = (unsigned short*)alloc((size_t)512 * 896 * 2);
  unsigned short* Wd_b  = (unsigned short*)alloc((size_t)256 * 512 * 2);

  hipMemsetAsync(d_ws, 0, misc_bytes, stream);

  // fused weight preprocessing (4 casts + Whh swizzle)
  {
    int total = 2688 * 512 + 512 * 896 + 256 * 512 + 256 * 256 + 224 * 28 * 512;
    k_prep<<<(total + 255) / 256, 256, 0, stream>>>(
        w_Wih, Wp, Wd, E, w_Whh, Wih_b, Wp_b, Wd_b, Eb, Whh_p);
  }

  // encoder
  k_gi_enc<<<128, 384, 0, stream>>>(x, m0f_Wih, m0f_bih, gi0f, 80);
  k_gi_enc<<<128, 384, 0, stream>>>(x, m0b_Wih, m0b_bih, gi0b, 80);
  k_scan_enc<<<2, 512, 0, stream>>>(gi0f, gi0b, m0f_Whh, m0f_bhh, m0b_Whh, m0b_bhh,
                                    c0, nullptr);
  k_gi_enc<<<128, 384, 0, stream>>>(c0, m1f_Wih, m1f_bih, gi1f, 256);
  k_gi_enc<<<128, 384, 0, stream>>>(c0, m1b_Wih, m1b_bih, gi1b, 256);
  k_scan_enc<<<2, 512, 0, stream>>>(gi1f, gi1b, m1f_Whh, m1f_bhh, m1b_Whh, m1b_bhh,
                                    c1, c1b);

  // gi GEMM: A fused from Eb/c1b/y, output written packed (includes bih)
  k_mgemm<<<dim3(80, 21), 256, 0, stream>>>(nullptr, Wih_b, w_bih, (void*)gpack,
                                            10240, 2688, 512, 0, 1, 1, 1, Eb, c1b, y);

  // recurrent wav GRU (elected single-XCD group, epoch protocol + LLC fallback)
  k_wav_rnn<<<NWG, 256, 0, stream>>>(Whh_p, w_bhh, gpack, ctl, hLd, hLe, hG, O32);

  // head
  k_mgemm<<<dim3(80, 4), 256, 0, stream>>>((const unsigned short*)O32, Wp_b, bp,
                                           (void*)O2, 10240, 512, 896, 1, 1, 0, 0,
                                           nullptr, nullptr, nullptr);
  k_mgemm<<<dim3(80, 2), 256, 0, stream>>>(O2, Wd_b, bd, (void*)LG,
                                           10240, 256, 512, 0, 0, 0, 0,
                                           nullptr, nullptr, nullptr);
  k_nll<<<2560, 256, 0, stream>>>(LG, y, PT);
  k_final<<<1, 256, 0, stream>>>(PT, (float*)d_out);
}

// Round 3
// 7846.588 us; speedup vs baseline: 1.1449x; 1.1449x over previous
//
#include <hip/hip_runtime.h>
#include <stdint.h>
#include <math.h>

typedef __attribute__((ext_vector_type(8))) short bf16x8;
typedef __attribute__((ext_vector_type(4))) float f32x4;
typedef __attribute__((ext_vector_type(4))) unsigned int u32x4;

#define BATCH 4
#define T_M 32
#define DE 128
#define T_W 2560
#define NWG 448       /* 448 blocks; 56 elected same-XCD workers, rest exit */
#define POLL_LIM 4096 /* local poll rounds before sticky fallback to LLC mirror */

__device__ __forceinline__ float b2f(unsigned short h) {
  return __uint_as_float(((unsigned int)h) << 16);
}
__device__ __forceinline__ unsigned short f2b(float f) {
  unsigned int u = __float_as_uint(f);
  u = u + 0x7fffu + ((u >> 16) & 1u);   // RNE
  return (unsigned short)(u >> 16);
}
__device__ __forceinline__ float blo(unsigned int u){ return __uint_as_float(u << 16); }
__device__ __forceinline__ float bhi(unsigned int u){ return __uint_as_float(u & 0xffff0000u); }
__device__ __forceinline__ float sigm(float x){
  return __builtin_amdgcn_rcpf(1.f + __expf(-x));
}
__device__ __forceinline__ float tanh_fast(float x){
  float x2 = fminf(fmaxf(x + x, -30.f), 30.f);
  return 1.f - 2.f * __builtin_amdgcn_rcpf(__expf(x2) + 1.f);
}
__device__ __forceinline__ float gelu_exact(float x){ return 0.5f * x * (1.f + erff(x * 0.70710678118654752f)); }

// ---------------- fused preprocessing: 4 bf16 casts + Whh swizzle ----------------
__global__ __launch_bounds__(256) void k_prep(
    const float* __restrict__ wih, const float* __restrict__ wp,
    const float* __restrict__ wd, const float* __restrict__ e,
    const float* __restrict__ whh,
    unsigned short* __restrict__ wih_b, unsigned short* __restrict__ wp_b,
    unsigned short* __restrict__ wd_b, unsigned short* __restrict__ eb,
    unsigned short* __restrict__ whh_p)
{
  int idx = blockIdx.x * 256 + threadIdx.x;
  const int N0 = 2688 * 512, N1 = 512 * 896, N2 = 256 * 512, N3 = 256 * 256;
  if (idx < N0) { wih_b[idx] = f2b(wih[idx]); return; }
  idx -= N0;
  if (idx < N1) { wp_b[idx] = f2b(wp[idx]); return; }
  idx -= N1;
  if (idx < N2) { wd_b[idx] = f2b(wd[idx]); return; }
  idx -= N2;
  if (idx < N3) { eb[idx] = f2b(e[idx]); return; }
  idx -= N3;
  if (idx >= 224 * 28 * 512) return;
  int j    = idx & 7;
  int r16  = (idx >> 3) & 15;
  int quad = (idx >> 7) & 3;
  int kc   = (idx >> 9) % 28;
  int G    = (idx >> 9) / 28;
  unsigned short val = 0;
  if (r16 < 12) {
    int row = (r16 >> 2) * 896 + G * 4 + (r16 & 3);
    int col = kc * 32 + quad * 8 + j;
    val = f2b(whh[(size_t)row * 896 + col]);
  }
  whh_p[idx] = val;
}

// ---------------- encoder: input projections gi = in @ Wih^T + bih (float4) ---------
__global__ __launch_bounds__(384) void k_gi_enc(
    const float* __restrict__ in, const float* __restrict__ Wih,
    const float* __restrict__ bih, float* __restrict__ out, int K)
{
  __shared__ float in_s[256];
  int tb = blockIdx.x;
  for (int i = threadIdx.x; i < K; i += 384) in_s[i] = in[tb * K + i];
  __syncthreads();
  int row = threadIdx.x;
  float acc = bih[row];
  const float* wr = Wih + row * K;
  for (int k = 0; k < K; k += 4) {
    float4 w = *(const float4*)(wr + k);
    float4 v = *(const float4*)(in_s + k);
    acc += w.x * v.x + w.y * v.y + w.z * v.z + w.w * v.w;
  }
  out[tb * 384 + row] = acc;
}

// ---------------- encoder: sequential scan, one WG per direction ----------------
// Phase 1: one thread per Whh row (384), computes all 4 batches (no redundant
// Whh re-reads). FP accumulation order per (row,b) identical to baseline.
__global__ __launch_bounds__(512) void k_scan_enc(
    const float* __restrict__ gi_f, const float* __restrict__ gi_b,
    const float* __restrict__ whh_f, const float* __restrict__ bhh_f,
    const float* __restrict__ whh_b, const float* __restrict__ bhh_b,
    float* __restrict__ c_out, unsigned short* __restrict__ cb)   // (32,4,256)
{
  const int dir = blockIdx.x, tid = threadIdx.x;
  const float* gi  = dir ? gi_b  : gi_f;
  const float* whh = dir ? whh_b : whh_f;
  const float* bhh = dir ? bhh_b : bhh_f;
  __shared__ unsigned short h_s[BATCH][DE + 8];
  __shared__ float gh_s[384][4];
  __shared__ float bhh_s[384];
  for (int i = tid; i < 384; i += 512) bhh_s[i] = bhh[i];
  for (int i = tid; i < BATCH * (DE + 8); i += 512) ((unsigned short*)h_s)[i] = 0;
  __syncthreads();
  for (int s = 0; s < T_M; ++s) {
    int t = dir ? (T_M - 1 - s) : s;
    if (tid < 384) {
      const float* wr = whh + tid * DE;
      float a0 = 0.f, a1 = 0.f, a2 = 0.f, a3 = 0.f;
      for (int j = 0; j < DE; j += 8) {
        float4 w0 = *(const float4*)(wr + j);
        float4 w1 = *(const float4*)(wr + j + 4);
        uint4 h0 = *(const uint4*)&h_s[0][j];
        uint4 h1 = *(const uint4*)&h_s[1][j];
        uint4 h2 = *(const uint4*)&h_s[2][j];
        uint4 h3 = *(const uint4*)&h_s[3][j];
        a0 += w0.x * blo(h0.x) + w0.y * bhi(h0.x) + w0.z * blo(h0.y) + w0.w * bhi(h0.y);
        a0 += w1.x * blo(h0.z) + w1.y * bhi(h0.z) + w1.z * blo(h0.w) + w1.w * bhi(h0.w);
        a1 += w0.x * blo(h1.x) + w0.y * bhi(h1.x) + w0.z * blo(h1.y) + w0.w * bhi(h1.y);
        a1 += w1.x * blo(h1.z) + w1.y * bhi(h1.z) + w1.z * blo(h1.w) + w1.w * bhi(h1.w);
        a2 += w0.x * blo(h2.x) + w0.y * bhi(h2.x) + w0.z * blo(h2.y) + w0.w * bhi(h2.y);
        a2 += w1.x * blo(h2.z) + w1.y * bhi(h2.z) + w1.z * blo(h2.w) + w1.w * bhi(h2.w);
        a3 += w0.x * blo(h3.x) + w0.y * bhi(h3.x) + w0.z * blo(h3.y) + w0.w * bhi(h3.y);
        a3 += w1.x * blo(h3.z) + w1.y * bhi(h3.z) + w1.z * blo(h3.w) + w1.w * bhi(h3.w);
      }
      float bb_ = bhh_s[tid];
      *(float4*)&gh_s[tid][0] = make_float4(a0 + bb_, a1 + bb_, a2 + bb_, a3 + bb_);
    }
    __syncthreads();
    {
      int u = tid >> 2, b = tid & 3;
      const float* git = gi + (t * BATCH + b) * 384;
      float r = sigm(git[u] + gh_s[u][b]);
      float z = sigm(git[DE + u] + gh_s[DE + u][b]);
      float n = tanh_fast(git[2 * DE + u] + r * gh_s[2 * DE + u][b]);
      float hold = b2f(h_s[b][u]);
      float hnew = (1.f - z) * n + z * hold;
      int oi = (t * BATCH + b) * 256 + dir * DE + u;
      c_out[oi] = hnew;
      if (cb) cb[oi] = f2b(hnew);
      h_s[b][u] = f2b(hnew);
    }
    __syncthreads();
  }
}

// ---------------- MFMA GEMM: C(MxN) = act(A(bf16 MxK) @ B(bf16 NxK)^T + bias) -------
__global__ __launch_bounds__(256) void k_mgemm(
    const unsigned short* __restrict__ A, const unsigned short* __restrict__ B,
    const float* __restrict__ bias, void* __restrict__ C,
    int M, int N, int K, int act, int c_bf16, int swz, int afuse,
    const unsigned short* __restrict__ Eb, const unsigned short* __restrict__ c1b,
    const float* __restrict__ yw)
{
  __shared__ unsigned short As[128][40];
  __shared__ unsigned short Bs[128][40];
  const int tid = threadIdx.x;
  const int m0 = blockIdx.x * 128, n0 = blockIdx.y * 128;
  const int lane = tid & 63, wave = tid >> 6;
  const int wy = wave >> 1, wx = wave & 1;
  const int row16 = lane & 15, quad = lane >> 4;
  const int sr = tid >> 1, sc = (tid & 1) * 16;
  const unsigned short* arow0 = nullptr;
  const unsigned short* arow1 = nullptr;
  if (afuse) {
    int row = m0 + sr, tt = row >> 2, b = row & 3;
    float w = (tt == 0) ? 0.f : yw[(tt - 1) * 4 + b];
    int q = (int)floorf((w + 1.f) * 128.f);
    q = q < 0 ? 0 : (q > 255 ? 255 : q);
    arow0 = Eb + q * 256;
    arow1 = c1b + ((tt / 80) * 4 + b) * 256;
  }
  f32x4 acc[4][4] = {};
  for (int kt = 0; kt < K; kt += 32) {
    uint4 av, av2;
    if (afuse) {
      int kk = kt + sc;
      const unsigned short* src = (kk < 256) ? (arow0 + kk) : (arow1 + kk - 256);
      av  = *(const uint4*)src;
      av2 = *(const uint4*)(src + 8);
    } else {
      av  = *(const uint4*)(A + (size_t)(m0 + sr) * K + kt + sc);
      av2 = *(const uint4*)(A + (size_t)(m0 + sr) * K + kt + sc + 8);
    }
    uint4 bv  = *(const uint4*)(B + (size_t)(n0 + sr) * K + kt + sc);
    uint4 bv2 = *(const uint4*)(B + (size_t)(n0 + sr) * K + kt + sc + 8);
    __syncthreads();
    *(uint4*)&As[sr][sc] = av; *(uint4*)&As[sr][sc + 8] = av2;
    *(uint4*)&Bs[sr][sc] = bv; *(uint4*)&Bs[sr][sc + 8] = bv2;
    __syncthreads();
    bf16x8 af[4], bf[4];
    #pragma unroll
    for (int i = 0; i < 4; ++i) af[i] = *(const bf16x8*)&As[wy * 64 + i * 16 + row16][quad * 8];
    #pragma unroll
    for (int j = 0; j < 4; ++j) bf[j] = *(const bf16x8*)&Bs[wx * 64 + j * 16 + row16][quad * 8];
    #pragma unroll
    for (int i = 0; i < 4; ++i)
      #pragma unroll
      for (int j = 0; j < 4; ++j)
        acc[i][j] = __builtin_amdgcn_mfma_f32_16x16x32_bf16(af[i], bf[j], acc[i][j], 0, 0, 0);
  }
  #pragma unroll
  for (int i = 0; i < 4; ++i) {
    #pragma unroll
    for (int j = 0; j < 4; ++j) {
      int col = n0 + wx * 64 + j * 16 + row16;
      float bs = bias[col];
      #pragma unroll
      for (int r = 0; r < 4; ++r) {
        int row = m0 + wy * 64 + i * 16 + quad * 4 + r;
        float v = acc[i][j][r] + bs;
        if (act) v = gelu_exact(v);
        if (swz) {
          int t = row >> 2, b = row & 3;
          int g = col / 896, rem = col - g * 896;
          int G = rem >> 2, u = rem & 3;
          ((unsigned short*)C)[(size_t)(t * 224 + G) * 48 + g * 16 + b * 4 + u] = f2b(v);
        } else if (c_bf16) {
          ((unsigned short*)C)[(size_t)row * N + col] = f2b(v);
        } else {
          ((float*)C)[(size_t)row * N + col] = v;
        }
      }
    }
  }
}

// ---------------- wav GRU: elected single-XCD group, baseline tagged protocol -------
// Election (proven r2): each block reads its XCD (HW_REG_XCC_ID), registers on a
// per-XCD arrival counter; first XCD to collect 56 blocks wins (CAS). Winner's
// ranks 0..55 work (provably same XCD); all other blocks exit. Timeout CAS
// forces mode 15 = blocks bid<56 work via the device-scope mirror (== baseline).
//
// Step protocol = round-0 baseline verbatim (ONE visibility hop, tag-in-packet,
// double buffer, self-validating poll), but packets go to an XCD-LOCAL buffer
// with sc0 (local L2 coherence point, ~2-3x lower latency than LLC) and are
// mirrored to a device-scope buffer (sc0 sc1). Per-wave sticky fallback to the
// mirror after POLL_LIM rounds; fast/fallback waves mix safely (same tags, same
// acquire-before-publish induction as baseline).
__global__ __launch_bounds__(256, 2) void k_wav_rnn(
    const unsigned short* __restrict__ whh_p,  // swizzled (224,28,4,16,8) bf16
    const float* __restrict__ bhh,             // (2688,)
    const unsigned short* __restrict__ gp_,    // packed gi (2560,224,3,4,4) bf16
    int* __restrict__ ctl,                     // [16] zeroed: 0..7 arrivals, 8 winner
    unsigned int* __restrict__ hloc,           // [2][896] 16B packets (zeroed)
    unsigned int* __restrict__ hglob,          // [2][896] 16B packets (zeroed)
    unsigned int* __restrict__ O32)            // (10240,448) dwords of bf16 pairs
{
  const int tid = threadIdx.x;
  const int lane = tid & 63, wave = tid >> 6;

  __shared__ int s_wg, s_mode;

  // ---- election ----
  int xcc;
  asm volatile("s_getreg_b32 %0, hwreg(HW_REG_XCC_ID)" : "=s"(xcc));
  xcc &= 7;
  if (tid == 0) {
    int rank = atomicAdd(&ctl[xcc], 1);
    if (rank == 55) atomicCAS(&ctl[8], 0, xcc + 1);
    int w, tries = 0;
    for (;;) {
      asm volatile("global_load_dword %0, %1, off sc0 sc1\ns_waitcnt vmcnt(0)"
                   : "=v"(w) : "v"((unsigned long long)&ctl[8]) : "memory");
      if (w) break;
      if (++tries > 20000) atomicCAS(&ctl[8], 0, 15);
    }
    if (w == 15) { s_mode = 1; s_wg = blockIdx.x; }
    else         { s_mode = 0; s_wg = (xcc == w - 1) ? rank : 999; }
  }
  __syncthreads();
  const int fmode = s_mode;
  const int wg = s_wg;
  if (wg >= 56) return;

  const int G = wg * 4 + wave;                 // global 4-unit group

  __shared__ unsigned short h_lds[2][4][912];  // h(t) double buffer, stride 1824B
  __shared__ float phh[4][3][4][4];            // [wave][gate][batch][unit]

  const int r16 = lane & 15, quad = lane >> 4, bb = lane & 3;
  const int fu = (lane >> 2) & 3, fb = lane & 3;   // finalize mapping (lanes 0-15 real)

  // ---- Whh fragments -> VGPRs (28 x bf16x8), coalesced 16B/lane ----
  bf16x8 wf[28];
  {
    const bf16x8* W8 = (const bf16x8*)whh_p + (size_t)G * 28 * 64;
    #pragma unroll
    for (int kc = 0; kc < 28; ++kc)
      wf[kc] = W8[(kc * 4 + quad) * 16 + r16];
  }

  // ---- per-lane bias + recurrent state ----
  const float br_ = bhh[G * 4 + fu];
  const float bz_ = bhh[896 + G * 4 + fu];
  const float bn_ = bhh[1792 + G * 4 + fu];
  float hprev = 0.f;
  const unsigned short* gl0 = gp_ + (size_t)G * 48 + fb * 4 + fu;
  unsigned short cr = gl0[0], cz = gl0[16], cn = gl0[32];   // gi(0), raw bf16 bits

  // ---- poll slice: thread covers packets tid, tid+256, tid+512, (tid+768 | dup) ----
  const int p0 = tid, p1 = tid + 256, p2 = tid + 512;
  const int p3 = (tid < 128) ? tid + 768 : tid;    // dup of own p0 when out of range
  const int pb0 = p0 / 224, pG0 = p0 - pb0 * 224;
  const int pb1 = p1 / 224, pG1 = p1 - pb1 * 224;
  const int pb2 = p2 / 224, pG2 = p2 - pb2 * 224;
  const int pb3 = p3 / 224, pG3 = p3 - pb3 * 224;

  const unsigned long long lb0 = (unsigned long long)hloc;
  const unsigned long long lb1 = lb0 + 14336ull;
  const unsigned long long gb0 = (unsigned long long)hglob;
  const unsigned long long gb1 = gb0 + 14336ull;

  int use_glob = fmode;   // sticky, wave-uniform fallback flag

  for (int t = 0; t < T_W; ++t) {
    // ---- poll my 4 packets (tags == t) ----
    unsigned long long hb = use_glob ? ((t & 1) ? gb1 : gb0)
                                     : ((t & 1) ? lb1 : lb0);
    unsigned long long a0 = hb + ((unsigned long long)p0 << 4);
    unsigned long long a1 = hb + ((unsigned long long)p1 << 4);
    unsigned long long a2 = hb + ((unsigned long long)p2 << 4);
    unsigned long long a3 = hb + ((unsigned long long)p3 << 4);
    u32x4 s0, s1, s2, s3;
    const unsigned int tg = (unsigned int)t;
    int tries = 0;
    for (;;) {
      if (!use_glob) {
        asm volatile(
          "global_load_dwordx4 %0, %4, off sc0\n"
          "global_load_dwordx4 %1, %5, off sc0\n"
          "global_load_dwordx4 %2, %6, off sc0\n"
          "global_load_dwordx4 %3, %7, off sc0\n"
          "s_waitcnt vmcnt(0)"
          : "=&v"(s0), "=&v"(s1), "=&v"(s2), "=&v"(s3)
          : "v"(a0), "v"(a1), "v"(a2), "v"(a3)
          : "memory");
      } else {
        asm volatile(
          "global_load_dwordx4 %0, %4, off sc0 sc1\n"
          "global_load_dwordx4 %1, %5, off sc0 sc1\n"
          "global_load_dwordx4 %2, %6, off sc0 sc1\n"
          "global_load_dwordx4 %3, %7, off sc0 sc1\n"
          "s_waitcnt vmcnt(0)"
          : "=&v"(s0), "=&v"(s1), "=&v"(s2), "=&v"(s3)
          : "v"(a0), "v"(a1), "v"(a2), "v"(a3)
          : "memory");
      }
      unsigned int bad = (s0.z ^ tg) | (s1.z ^ tg) | (s2.z ^ tg) | (s3.z ^ tg);
      if (!__any(bad != 0)) break;
      if (!use_glob && ++tries > POLL_LIM) {
        use_glob = 1;                      // wave-uniform (tries is uniform)
        hb = (t & 1) ? gb1 : gb0;
        a0 = hb + ((unsigned long long)p0 << 4);
        a1 = hb + ((unsigned long long)p1 << 4);
        a2 = hb + ((unsigned long long)p2 << 4);
        a3 = hb + ((unsigned long long)p3 << 4);
      }
    }

    // ---- issue gi(t+1) loads now (raw bf16 bits; consumed at next finalize) ----
    int tn = (t + 1 < T_W) ? (t + 1) : t;
    const unsigned short* gp = gp_ + (size_t)tn * 10752 + G * 48 + fb * 4 + fu;
    unsigned short nr_ = gp[0], nz_ = gp[16], nn_ = gp[32];

    // ---- scatter h(t) into LDS buffer t&1 ----
    *(uint2*)&h_lds[t & 1][pb0][pG0 * 4] = make_uint2(s0.x, s0.y);
    *(uint2*)&h_lds[t & 1][pb1][pG1 * 4] = make_uint2(s1.x, s1.y);
    *(uint2*)&h_lds[t & 1][pb2][pG2 * 4] = make_uint2(s2.x, s2.y);
    *(uint2*)&h_lds[t & 1][pb3][pG3 * 4] = make_uint2(s3.x, s3.y);
    __syncthreads();   // single barrier: h(t) fully in LDS

    // ---- 28 MFMAs, 4 interleaved accumulator chains ----
    f32x4 ac0 = {}, ac1 = {}, ac2 = {}, ac3 = {};
    #pragma unroll
    for (int kc = 0; kc < 28; kc += 4) {
      bf16x8 h0 = *(const bf16x8*)&h_lds[t & 1][bb][(kc + 0) * 32 + quad * 8];
      bf16x8 h1 = *(const bf16x8*)&h_lds[t & 1][bb][(kc + 1) * 32 + quad * 8];
      bf16x8 h2 = *(const bf16x8*)&h_lds[t & 1][bb][(kc + 2) * 32 + quad * 8];
      bf16x8 h3 = *(const bf16x8*)&h_lds[t & 1][bb][(kc + 3) * 32 + quad * 8];
      ac0 = __builtin_amdgcn_mfma_f32_16x16x32_bf16(wf[kc + 0], h0, ac0, 0, 0, 0);
      ac1 = __builtin_amdgcn_mfma_f32_16x16x32_bf16(wf[kc + 1], h1, ac1, 0, 0, 0);
      ac2 = __builtin_amdgcn_mfma_f32_16x16x32_bf16(wf[kc + 2], h2, ac2, 0, 0, 0);
      ac3 = __builtin_amdgcn_mfma_f32_16x16x32_bf16(wf[kc + 3], h3, ac3, 0, 0, 0);
    }
    f32x4 ac;
    ac[0] = ac0[0] + ac1[0] + ac2[0] + ac3[0];
    ac[1] = ac0[1] + ac1[1] + ac2[1] + ac3[1];
    ac[2] = ac0[2] + ac1[2] + ac2[2] + ac3[2];
    ac[3] = ac0[3] + ac1[3] + ac2[3] + ac3[3];

    // ---- in-wave transpose via LDS: D[row=quad*4+reg][col=r16] -> phh[v][g][b][u] ----
    if (r16 < 4 && quad < 3)
      *(f32x4*)&phh[wave][quad][r16][0] = ac;
    asm volatile("s_waitcnt lgkmcnt(0)" ::: "memory");   // same-wave DS in-order

    // ---- finalize my 16 h values (lanes 0-15; others duplicate harmlessly) ----
    float pr = phh[wave][0][fb][fu];
    float pz = phh[wave][1][fb][fu];
    float pn = phh[wave][2][fb][fu];
    float r = sigm(b2f(cr) + br_ + pr);
    float z = sigm(b2f(cz) + bz_ + pz);
    float n = tanh_fast(b2f(cn) + bn_ + r * pn);
    float h = (1.f - z) * n + z * hprev;
    hprev = h;
    unsigned int hu = f2b(h);
    cr = nr_; cz = nz_; cn = nn_;

    // ---- publish: lanes 0-3 own packet (batch b = lane) ----
    int b = lane & 3;
    unsigned int u0v = (unsigned int)__shfl((int)hu, 0 + b);
    unsigned int u1v = (unsigned int)__shfl((int)hu, 4 + b);
    unsigned int u2v = (unsigned int)__shfl((int)hu, 8 + b);
    unsigned int u3v = (unsigned int)__shfl((int)hu, 12 + b);
    if (lane < 4) {
      u32x4 pkt;
      pkt.x = (u0v & 0xffffu) | (u1v << 16);
      pkt.y = (u2v & 0xffffu) | (u3v << 16);
      pkt.z = (unsigned int)(t + 1);
      pkt.w = 0u;
      const unsigned long long off4 = (unsigned long long)((b * 224 + G) << 4);
      const int par = (t + 1) & 1;
      if (!fmode) {
        unsigned long long sl = (par ? lb1 : lb0) + off4;   // XCD-local fast path
        asm volatile("global_store_dwordx4 %0, %1, off sc0"
                     :: "v"(sl), "v"(pkt) : "memory");
      }
      unsigned long long sg = (par ? gb1 : gb0) + off4;     // device-scope mirror
      asm volatile("global_store_dwordx4 %0, %1, off sc0 sc1"
                   :: "v"(sg), "v"(pkt) : "memory");
      *(uint2*)(O32 + (size_t)(t * 4 + b) * 448 + G * 2) = make_uint2(pkt.x, pkt.y);
    }
  }
}

// ---------------- NLL: per-block reduction, NO atomics ----------------
__global__ __launch_bounds__(256) void k_nll(
    const float* __restrict__ logits, const float* __restrict__ y,
    float* __restrict__ partials)
{
  __shared__ float ps[4];
  int wid = threadIdx.x >> 6, lane = threadIdx.x & 63;
  int row = blockIdx.x * 4 + wid;
  const float* lr = logits + (size_t)row * 256;
  float v0 = lr[lane], v1 = lr[lane + 64], v2 = lr[lane + 128], v3 = lr[lane + 192];
  float mx = fmaxf(fmaxf(v0, v1), fmaxf(v2, v3));
  for (int off = 32; off > 0; off >>= 1) mx = fmaxf(mx, __shfl_xor(mx, off));
  float se = __expf(v0 - mx) + __expf(v1 - mx) + __expf(v2 - mx) + __expf(v3 - mx);
  for (int off = 32; off > 0; off >>= 1) se += __shfl_xor(se, off);
  if (lane == 0) {
    float w = y[row];
    int q = (int)floorf((w + 1.f) * 128.f);
    q = q < 0 ? 0 : (q > 255 ? 255 : q);
    ps[wid] = (logf(se) + mx) - lr[q];
  }
  __syncthreads();
  if (threadIdx.x == 0) partials[blockIdx.x] = ps[0] + ps[1] + ps[2] + ps[3];
}

__global__ __launch_bounds__(256) void k_final(const float* __restrict__ partials,
                                               float* __restrict__ out)
{
  __shared__ float s[4];
  int tid = threadIdx.x;
  float a = 0.f;
  for (int i = tid; i < 2560; i += 256) a += partials[i];
  for (int off = 32; off > 0; off >>= 1) a += __shfl_xor(a, off);
  if ((tid & 63) == 0) s[tid >> 6] = a;
  __syncthreads();
  if (tid == 0) out[0] = (s[0] + s[1] + s[2] + s[3]) * (1.f / 10240.f);
}

// ---------------- host ----------------
extern "C" void kernel_launch(void* const* d_in, const int* in_sizes, int n_in,
                              void* d_out, int out_size, void* d_ws, size_t ws_size,
                              hipStream_t stream)
{
  const float* x       = (const float*)d_in[0];
  const float* y       = (const float*)d_in[1];
  const float* m0f_Wih = (const float*)d_in[2];
  const float* m0f_Whh = (const float*)d_in[3];
  const float* m0f_bih = (const float*)d_in[4];
  const float* m0f_bhh = (const float*)d_in[5];
  const float* m0b_Wih = (const float*)d_in[6];
  const float* m0b_Whh = (const float*)d_in[7];
  const float* m0b_bih = (const float*)d_in[8];
  const float* m0b_bhh = (const float*)d_in[9];
  const float* m1f_Wih = (const float*)d_in[10];
  const float* m1f_Whh = (const float*)d_in[11];
  const float* m1f_bih = (const float*)d_in[12];
  const float* m1f_bhh = (const float*)d_in[13];
  const float* m1b_Wih = (const float*)d_in[14];
  const float* m1b_Whh = (const float*)d_in[15];
  const float* m1b_bih = (const float*)d_in[16];
  const float* m1b_bhh = (const float*)d_in[17];
  const float* w_Wih   = (const float*)d_in[18];
  const float* w_Whh   = (const float*)d_in[19];
  const float* w_bih   = (const float*)d_in[20];
  const float* w_bhh   = (const float*)d_in[21];
  const float* Wp      = (const float*)d_in[22];
  const float* bp      = (const float*)d_in[23];
  const float* E       = (const float*)d_in[24];
  const float* Wd      = (const float*)d_in[25];
  const float* bd      = (const float*)d_in[26];

  char* ws = (char*)d_ws;
  size_t off = 0;
  auto alloc = [&](size_t bytes) -> void* {
    void* p = ws + off;
    off += (bytes + 255) & ~(size_t)255;
    return p;
  };
  // misc (zeroed each launch): election ctl + local/mirror packet buffers
  int*          ctl   = (int*)alloc(16 * 4);
  unsigned int* hloc  = (unsigned int*)alloc((size_t)2 * 896 * 16);
  unsigned int* hglob = (unsigned int*)alloc((size_t)2 * 896 * 16);
  size_t misc_bytes = off;

  float* c0   = (float*)alloc((size_t)32 * 4 * 256 * 4);
  float* c1   = (float*)alloc((size_t)32 * 4 * 256 * 4);
  float* gi0f = (float*)alloc((size_t)32 * 4 * 384 * 4);
  float* gi0b = (float*)alloc((size_t)32 * 4 * 384 * 4);
  float* gi1f = (float*)alloc((size_t)32 * 4 * 384 * 4);
  float* gi1b = (float*)alloc((size_t)32 * 4 * 384 * 4);
  unsigned short* Eb    = (unsigned short*)alloc((size_t)256 * 256 * 2);
  unsigned short* c1b   = (unsigned short*)alloc((size_t)32 * 4 * 256 * 2);
  unsigned short* gpack = (unsigned short*)alloc((size_t)2560 * 224 * 48 * 2);
  unsigned int*   O32   = (unsigned int*)alloc((size_t)10240 * 448 * 4);
  unsigned short* O2    = (unsigned short*)alloc((size_t)10240 * 512 * 2);
  float*          LG    = (float*)alloc((size_t)10240 * 256 * 4);
  float*          PT    = (float*)alloc((size_t)2560 * 4);
  unsigned short* Wih_b = (unsigned short*)alloc((size_t)2688 * 512 * 2);
  unsigned short* Whh_p = (unsigned short*)alloc((size_t)224 * 28 * 512 * 2);
  unsigned short* Wp_b  = (unsigned short*)alloc((size_t)512 * 896 * 2);
  unsigned short* Wd_b  = (unsigned short*)alloc((size_t)256 * 512 * 2);

  hipMemsetAsync(d_ws, 0, misc_bytes, stream);

  // fused weight preprocessing (4 casts + Whh swizzle)
  {
    int total = 2688 * 512 + 512 * 896 + 256 * 512 + 256 * 256 + 224 * 28 * 512;
    k_prep<<<(total + 255) / 256, 256, 0, stream>>>(
        w_Wih, Wp, Wd, E, w_Whh, Wih_b, Wp_b, Wd_b, Eb, Whh_p);
  }

  // encoder
  k_gi_enc<<<128, 384, 0, stream>>>(x, m0f_Wih, m0f_bih, gi0f, 80);
  k_gi_enc<<<128, 384, 0, stream>>>(x, m0b_Wih, m0b_bih, gi0b, 80);
  k_scan_enc<<<2, 512, 0, stream>>>(gi0f, gi0b, m0f_Whh, m0f_bhh, m0b_Whh, m0b_bhh,
                                    c0, nullptr);
  k_gi_enc<<<128, 384, 0, stream>>>(c0, m1f_Wih, m1f_bih, gi1f, 256);
  k_gi_enc<<<128, 384, 0, stream>>>(c0, m1b_Wih, m1b_bih, gi1b, 256);
  k_scan_enc<<<2, 512, 0, stream>>>(gi1f, gi1b, m1f_Whh, m1f_bhh, m1b_Whh, m1b_bhh,
                                    c1, c1b);

  // gi GEMM: A fused from Eb/c1b/y, output written packed (includes bih)
  k_mgemm<<<dim3(80, 21), 256, 0, stream>>>(nullptr, Wih_b, w_bih, (void*)gpack,
                                            10240, 2688, 512, 0, 1, 1, 1, Eb, c1b, y);

  // recurrent wav GRU (elected single-XCD group, baseline tagged protocol, local L2)
  k_wav_rnn<<<NWG, 256, 0, stream>>>(Whh_p, w_bhh, gpack, ctl, hloc, hglob, O32);

  // head
  k_mgemm<<<dim3(80, 4), 256, 0, stream>>>((const unsigned short*)O32, Wp_b, bp,
                                           (void*)O2, 10240, 512, 896, 1, 1, 0, 0,
                                           nullptr, nullptr, nullptr);
  k_mgemm<<<dim3(80, 2), 256, 0, stream>>>(O2, Wd_b, bd, (void*)LG,
                                           10240, 256, 512, 0, 0, 0, 0,
                                           nullptr, nullptr, nullptr);
  k_nll<<<2560, 256, 0, stream>>>(LG, y, PT);
  k_final<<<1, 256, 0, stream>>>(PT, (float*)d_out);
}

// Round 4
// 5519.724 us; speedup vs baseline: 1.6275x; 1.4216x over previous
//
#include <hip/hip_runtime.h>
#include <stdint.h>
#include <math.h>

typedef __attribute__((ext_vector_type(8))) short bf16x8;
typedef __attribute__((ext_vector_type(4))) float f32x4;
typedef __attribute__((ext_vector_type(4))) unsigned int u32x4;

#define BATCH 4
#define T_M 32
#define DE 128
#define T_W 2560
#define NWG 56        /* wav-rnn WGs; 4 waves each; wave owns 4 units; 56*4*4 = 896 */

__device__ __forceinline__ float b2f(unsigned short h) {
  return __uint_as_float(((unsigned int)h) << 16);
}
__device__ __forceinline__ unsigned short f2b(float f) {
  unsigned int u = __float_as_uint(f);
  u = u + 0x7fffu + ((u >> 16) & 1u);   // RNE
  return (unsigned short)(u >> 16);
}
__device__ __forceinline__ float blo(unsigned int u){ return __uint_as_float(u << 16); }
__device__ __forceinline__ float bhi(unsigned int u){ return __uint_as_float(u & 0xffff0000u); }
__device__ __forceinline__ float sigm(float x){
  return __builtin_amdgcn_rcpf(1.f + __expf(-x));
}
__device__ __forceinline__ float tanh_fast(float x){
  float x2 = fminf(fmaxf(x + x, -30.f), 30.f);
  return 1.f - 2.f * __builtin_amdgcn_rcpf(__expf(x2) + 1.f);
}
__device__ __forceinline__ float gelu_exact(float x){ return 0.5f * x * (1.f + erff(x * 0.70710678118654752f)); }

// ---------------- fused preprocessing: 4 bf16 casts + Whh swizzle ----------------
__global__ __launch_bounds__(256) void k_prep(
    const float* __restrict__ wih, const float* __restrict__ wp,
    const float* __restrict__ wd, const float* __restrict__ e,
    const float* __restrict__ whh,
    unsigned short* __restrict__ wih_b, unsigned short* __restrict__ wp_b,
    unsigned short* __restrict__ wd_b, unsigned short* __restrict__ eb,
    unsigned short* __restrict__ whh_p)
{
  int idx = blockIdx.x * 256 + threadIdx.x;
  const int N0 = 2688 * 512, N1 = 512 * 896, N2 = 256 * 512, N3 = 256 * 256;
  if (idx < N0) { wih_b[idx] = f2b(wih[idx]); return; }
  idx -= N0;
  if (idx < N1) { wp_b[idx] = f2b(wp[idx]); return; }
  idx -= N1;
  if (idx < N2) { wd_b[idx] = f2b(wd[idx]); return; }
  idx -= N2;
  if (idx < N3) { eb[idx] = f2b(e[idx]); return; }
  idx -= N3;
  if (idx >= 224 * 28 * 512) return;
  int j    = idx & 7;
  int r16  = (idx >> 3) & 15;
  int quad = (idx >> 7) & 3;
  int kc   = (idx >> 9) % 28;
  int G    = (idx >> 9) / 28;
  unsigned short val = 0;
  if (r16 < 12) {
    int row = (r16 >> 2) * 896 + G * 4 + (r16 & 3);
    int col = kc * 32 + quad * 8 + j;
    val = f2b(whh[(size_t)row * 896 + col]);
  }
  whh_p[idx] = val;
}

// ---------------- encoder: input projections gi = in @ Wih^T + bih (float4) ---------
__global__ __launch_bounds__(384) void k_gi_enc(
    const float* __restrict__ in, const float* __restrict__ Wih,
    const float* __restrict__ bih, float* __restrict__ out, int K)
{
  __shared__ float in_s[256];
  int tb = blockIdx.x;
  for (int i = threadIdx.x; i < K; i += 384) in_s[i] = in[tb * K + i];
  __syncthreads();
  int row = threadIdx.x;
  float acc = bih[row];
  const float* wr = Wih + row * K;
  for (int k = 0; k < K; k += 4) {
    float4 w = *(const float4*)(wr + k);
    float4 v = *(const float4*)(in_s + k);
    acc += w.x * v.x + w.y * v.y + w.z * v.z + w.w * v.w;
  }
  out[tb * 384 + row] = acc;
}

// ---------------- encoder: sequential scan, one WG per direction ----------------
// Phase 1: one thread per Whh row (384), computes all 4 batches (no redundant
// Whh re-reads). FP accumulation order per (row,b) identical to baseline.
__global__ __launch_bounds__(512) void k_scan_enc(
    const float* __restrict__ gi_f, const float* __restrict__ gi_b,
    const float* __restrict__ whh_f, const float* __restrict__ bhh_f,
    const float* __restrict__ whh_b, const float* __restrict__ bhh_b,
    float* __restrict__ c_out, unsigned short* __restrict__ cb)   // (32,4,256)
{
  const int dir = blockIdx.x, tid = threadIdx.x;
  const float* gi  = dir ? gi_b  : gi_f;
  const float* whh = dir ? whh_b : whh_f;
  const float* bhh = dir ? bhh_b : bhh_f;
  __shared__ unsigned short h_s[BATCH][DE + 8];
  __shared__ float gh_s[384][4];
  __shared__ float bhh_s[384];
  for (int i = tid; i < 384; i += 512) bhh_s[i] = bhh[i];
  for (int i = tid; i < BATCH * (DE + 8); i += 512) ((unsigned short*)h_s)[i] = 0;
  __syncthreads();
  for (int s = 0; s < T_M; ++s) {
    int t = dir ? (T_M - 1 - s) : s;
    if (tid < 384) {
      const float* wr = whh + tid * DE;
      float a0 = 0.f, a1 = 0.f, a2 = 0.f, a3 = 0.f;
      for (int j = 0; j < DE; j += 8) {
        float4 w0 = *(const float4*)(wr + j);
        float4 w1 = *(const float4*)(wr + j + 4);
        uint4 h0 = *(const uint4*)&h_s[0][j];
        uint4 h1 = *(const uint4*)&h_s[1][j];
        uint4 h2 = *(const uint4*)&h_s[2][j];
        uint4 h3 = *(const uint4*)&h_s[3][j];
        a0 += w0.x * blo(h0.x) + w0.y * bhi(h0.x) + w0.z * blo(h0.y) + w0.w * bhi(h0.y);
        a0 += w1.x * blo(h0.z) + w1.y * bhi(h0.z) + w1.z * blo(h0.w) + w1.w * bhi(h0.w);
        a1 += w0.x * blo(h1.x) + w0.y * bhi(h1.x) + w0.z * blo(h1.y) + w0.w * bhi(h1.y);
        a1 += w1.x * blo(h1.z) + w1.y * bhi(h1.z) + w1.z * blo(h1.w) + w1.w * bhi(h1.w);
        a2 += w0.x * blo(h2.x) + w0.y * bhi(h2.x) + w0.z * blo(h2.y) + w0.w * bhi(h2.y);
        a2 += w1.x * blo(h2.z) + w1.y * bhi(h2.z) + w1.z * blo(h2.w) + w1.w * bhi(h2.w);
        a3 += w0.x * blo(h3.x) + w0.y * bhi(h3.x) + w0.z * blo(h3.y) + w0.w * bhi(h3.y);
        a3 += w1.x * blo(h3.z) + w1.y * bhi(h3.z) + w1.z * blo(h3.w) + w1.w * bhi(h3.w);
      }
      float bb_ = bhh_s[tid];
      *(float4*)&gh_s[tid][0] = make_float4(a0 + bb_, a1 + bb_, a2 + bb_, a3 + bb_);
    }
    __syncthreads();
    {
      int u = tid >> 2, b = tid & 3;
      const float* git = gi + (t * BATCH + b) * 384;
      float r = sigm(git[u] + gh_s[u][b]);
      float z = sigm(git[DE + u] + gh_s[DE + u][b]);
      float n = tanh_fast(git[2 * DE + u] + r * gh_s[2 * DE + u][b]);
      float hold = b2f(h_s[b][u]);
      float hnew = (1.f - z) * n + z * hold;
      int oi = (t * BATCH + b) * 256 + dir * DE + u;
      c_out[oi] = hnew;
      if (cb) cb[oi] = f2b(hnew);
      h_s[b][u] = f2b(hnew);
    }
    __syncthreads();
  }
}

// ---------------- MFMA GEMM: C(MxN) = act(A(bf16 MxK) @ B(bf16 NxK)^T + bias) -------
__global__ __launch_bounds__(256) void k_mgemm(
    const unsigned short* __restrict__ A, const unsigned short* __restrict__ B,
    const float* __restrict__ bias, void* __restrict__ C,
    int M, int N, int K, int act, int c_bf16, int swz, int afuse,
    const unsigned short* __restrict__ Eb, const unsigned short* __restrict__ c1b,
    const float* __restrict__ yw)
{
  __shared__ unsigned short As[128][40];
  __shared__ unsigned short Bs[128][40];
  const int tid = threadIdx.x;
  const int m0 = blockIdx.x * 128, n0 = blockIdx.y * 128;
  const int lane = tid & 63, wave = tid >> 6;
  const int wy = wave >> 1, wx = wave & 1;
  const int row16 = lane & 15, quad = lane >> 4;
  const int sr = tid >> 1, sc = (tid & 1) * 16;
  const unsigned short* arow0 = nullptr;
  const unsigned short* arow1 = nullptr;
  if (afuse) {
    int row = m0 + sr, tt = row >> 2, b = row & 3;
    float w = (tt == 0) ? 0.f : yw[(tt - 1) * 4 + b];
    int q = (int)floorf((w + 1.f) * 128.f);
    q = q < 0 ? 0 : (q > 255 ? 255 : q);
    arow0 = Eb + q * 256;
    arow1 = c1b + ((tt / 80) * 4 + b) * 256;
  }
  f32x4 acc[4][4] = {};
  for (int kt = 0; kt < K; kt += 32) {
    uint4 av, av2;
    if (afuse) {
      int kk = kt + sc;
      const unsigned short* src = (kk < 256) ? (arow0 + kk) : (arow1 + kk - 256);
      av  = *(const uint4*)src;
      av2 = *(const uint4*)(src + 8);
    } else {
      av  = *(const uint4*)(A + (size_t)(m0 + sr) * K + kt + sc);
      av2 = *(const uint4*)(A + (size_t)(m0 + sr) * K + kt + sc + 8);
    }
    uint4 bv  = *(const uint4*)(B + (size_t)(n0 + sr) * K + kt + sc);
    uint4 bv2 = *(const uint4*)(B + (size_t)(n0 + sr) * K + kt + sc + 8);
    __syncthreads();
    *(uint4*)&As[sr][sc] = av; *(uint4*)&As[sr][sc + 8] = av2;
    *(uint4*)&Bs[sr][sc] = bv; *(uint4*)&Bs[sr][sc + 8] = bv2;
    __syncthreads();
    bf16x8 af[4], bf[4];
    #pragma unroll
    for (int i = 0; i < 4; ++i) af[i] = *(const bf16x8*)&As[wy * 64 + i * 16 + row16][quad * 8];
    #pragma unroll
    for (int j = 0; j < 4; ++j) bf[j] = *(const bf16x8*)&Bs[wx * 64 + j * 16 + row16][quad * 8];
    #pragma unroll
    for (int i = 0; i < 4; ++i)
      #pragma unroll
      for (int j = 0; j < 4; ++j)
        acc[i][j] = __builtin_amdgcn_mfma_f32_16x16x32_bf16(af[i], bf[j], acc[i][j], 0, 0, 0);
  }
  #pragma unroll
  for (int i = 0; i < 4; ++i) {
    #pragma unroll
    for (int j = 0; j < 4; ++j) {
      int col = n0 + wx * 64 + j * 16 + row16;
      float bs = bias[col];
      #pragma unroll
      for (int r = 0; r < 4; ++r) {
        int row = m0 + wy * 64 + i * 16 + quad * 4 + r;
        float v = acc[i][j][r] + bs;
        if (act) v = gelu_exact(v);
        if (swz) {
          int t = row >> 2, b = row & 3;
          int g = col / 896, rem = col - g * 896;
          int G = rem >> 2, u = rem & 3;
          ((unsigned short*)C)[(size_t)(t * 224 + G) * 48 + g * 16 + b * 4 + u] = f2b(v);
        } else if (c_bf16) {
          ((unsigned short*)C)[(size_t)row * N + col] = f2b(v);
        } else {
          ((float*)C)[(size_t)row * N + col] = v;
        }
      }
    }
  }
}

// ---------------- wav GRU: 56 WGs x 4 waves; wave owns G (4 units) ------------------
// Round-0 LLC protocol (tag-in-packet, double buffer, sc0 sc1) with ONE change:
// SPARSE RE-POLL. Each thread tracks which of its 4 packets already matched the
// tag and re-loads only the stragglers. A 16B packet is a single transaction and
// its tag transitions monotonically (t-1 -> t), so a matched payload is final.
// Round 1 reads the full set; later rounds read <1KB instead of 16KB per WG,
// removing the LLC/HBM poll storm that inflated round-trip latency (r0 FETCH
// showed ~3 full-set HBM re-reads per step) and that saturated the single-XCD
// L2 in r3.
__global__ __launch_bounds__(256, 1) void k_wav_rnn(
    const unsigned short* __restrict__ whh_p,  // swizzled (224,28,4,16,8) bf16
    const float* __restrict__ bhh,             // (2688,)
    const unsigned short* __restrict__ gp_,    // packed gi (2560,224,3,4,4) bf16
    unsigned int* __restrict__ hslots,         // 2*896 packets of 16B, zeroed
    unsigned int* __restrict__ O32)            // (10240,448) dwords of bf16 pairs
{
  const int wg = blockIdx.x, tid = threadIdx.x;
  const int lane = tid & 63, wave = tid >> 6;
  const int G = wg * 4 + wave;                 // global 4-unit group

  __shared__ unsigned short h_lds[2][4][912];  // h(t) double buffer, stride 1824B
  __shared__ float phh[4][3][4][4];            // [wave][gate][batch][unit]

  const int r16 = lane & 15, quad = lane >> 4, bb = lane & 3;
  const int fu = (lane >> 2) & 3, fb = lane & 3;   // finalize mapping (lanes 0-15 real)

  // ---- Whh fragments -> VGPRs (28 x bf16x8 = 112 VGPRs), coalesced 16B/lane ----
  bf16x8 wf[28];
  {
    const bf16x8* W8 = (const bf16x8*)whh_p + (size_t)G * 28 * 64;
    #pragma unroll
    for (int kc = 0; kc < 28; ++kc)
      wf[kc] = W8[(kc * 4 + quad) * 16 + r16];
  }

  // ---- per-lane bias + recurrent state ----
  const float br_ = bhh[G * 4 + fu];
  const float bz_ = bhh[896 + G * 4 + fu];
  const float bn_ = bhh[1792 + G * 4 + fu];
  float hprev = 0.f;
  const unsigned short* gl0 = gp_ + (size_t)G * 48 + fb * 4 + fu;
  unsigned short cr = gl0[0], cz = gl0[16], cn = gl0[32];   // gi(0), raw bf16 bits

  // ---- poll slice: thread covers packets tid, tid+256, tid+512, (tid+768 | dup) ----
  const int p0 = tid, p1 = tid + 256, p2 = tid + 512;
  const int p3 = (tid < 128) ? tid + 768 : tid;    // dup of own p0 when out of range
  const int pb0 = p0 / 224, pG0 = p0 - pb0 * 224;
  const int pb1 = p1 / 224, pG1 = p1 - pb1 * 224;
  const int pb2 = p2 / 224, pG2 = p2 - pb2 * 224;
  const int pb3 = p3 / 224, pG3 = p3 - pb3 * 224;

  const unsigned long long base0 = (unsigned long long)hslots;
  const unsigned long long base1 = base0 + 14336ull;

  for (int t = 0; t < T_W; ++t) {
    // ---- poll my 4 packets (tags == t); re-load only stragglers ----
    const unsigned long long hb = (t & 1) ? base1 : base0;
    unsigned long long a0 = hb + ((unsigned long long)p0 << 4);
    unsigned long long a1 = hb + ((unsigned long long)p1 << 4);
    unsigned long long a2 = hb + ((unsigned long long)p2 << 4);
    unsigned long long a3 = hb + ((unsigned long long)p3 << 4);
    u32x4 s0 = {}, s1 = {}, s2 = {}, s3 = {};
    const unsigned int tg = (unsigned int)t;
    bool n0 = true, n1 = true, n2 = true, n3 = true;
    for (;;) {
      if (n0) asm volatile("global_load_dwordx4 %0, %1, off sc0 sc1"
                           : "+v"(s0) : "v"(a0) : "memory");
      if (n1) asm volatile("global_load_dwordx4 %0, %1, off sc0 sc1"
                           : "+v"(s1) : "v"(a1) : "memory");
      if (n2) asm volatile("global_load_dwordx4 %0, %1, off sc0 sc1"
                           : "+v"(s2) : "v"(a2) : "memory");
      if (n3) asm volatile("global_load_dwordx4 %0, %1, off sc0 sc1"
                           : "+v"(s3) : "v"(a3) : "memory");
      asm volatile("s_waitcnt vmcnt(0)" ::: "memory");
      n0 = (s0.z != tg); n1 = (s1.z != tg); n2 = (s2.z != tg); n3 = (s3.z != tg);
      if (!__any(n0 | n1 | n2 | n3)) break;
    }

    // ---- issue gi(t+1) loads now (raw bf16 bits; consumed at next finalize) ----
    int tn = (t + 1 < T_W) ? (t + 1) : t;
    const unsigned short* gp = gp_ + (size_t)tn * 10752 + G * 48 + fb * 4 + fu;
    unsigned short nr_ = gp[0], nz_ = gp[16], nn_ = gp[32];

    // ---- scatter h(t) into LDS buffer t&1 ----
    *(uint2*)&h_lds[t & 1][pb0][pG0 * 4] = make_uint2(s0.x, s0.y);
    *(uint2*)&h_lds[t & 1][pb1][pG1 * 4] = make_uint2(s1.x, s1.y);
    *(uint2*)&h_lds[t & 1][pb2][pG2 * 4] = make_uint2(s2.x, s2.y);
    *(uint2*)&h_lds[t & 1][pb3][pG3 * 4] = make_uint2(s3.x, s3.y);
    __syncthreads();   // single barrier: h(t) fully in LDS

    // ---- 28 MFMAs, 4 interleaved accumulator chains ----
    f32x4 ac0 = {}, ac1 = {}, ac2 = {}, ac3 = {};
    #pragma unroll
    for (int kc = 0; kc < 28; kc += 4) {
      bf16x8 h0 = *(const bf16x8*)&h_lds[t & 1][bb][(kc + 0) * 32 + quad * 8];
      bf16x8 h1 = *(const bf16x8*)&h_lds[t & 1][bb][(kc + 1) * 32 + quad * 8];
      bf16x8 h2 = *(const bf16x8*)&h_lds[t & 1][bb][(kc + 2) * 32 + quad * 8];
      bf16x8 h3 = *(const bf16x8*)&h_lds[t & 1][bb][(kc + 3) * 32 + quad * 8];
      ac0 = __builtin_amdgcn_mfma_f32_16x16x32_bf16(wf[kc + 0], h0, ac0, 0, 0, 0);
      ac1 = __builtin_amdgcn_mfma_f32_16x16x32_bf16(wf[kc + 1], h1, ac1, 0, 0, 0);
      ac2 = __builtin_amdgcn_mfma_f32_16x16x32_bf16(wf[kc + 2], h2, ac2, 0, 0, 0);
      ac3 = __builtin_amdgcn_mfma_f32_16x16x32_bf16(wf[kc + 3], h3, ac3, 0, 0, 0);
    }
    f32x4 ac;
    ac[0] = ac0[0] + ac1[0] + ac2[0] + ac3[0];
    ac[1] = ac0[1] + ac1[1] + ac2[1] + ac3[1];
    ac[2] = ac0[2] + ac1[2] + ac2[2] + ac3[2];
    ac[3] = ac0[3] + ac1[3] + ac2[3] + ac3[3];

    // ---- in-wave transpose via LDS: D[row=quad*4+reg][col=r16] -> phh[v][g][b][u] ----
    if (r16 < 4 && quad < 3)
      *(f32x4*)&phh[wave][quad][r16][0] = ac;
    asm volatile("s_waitcnt lgkmcnt(0)" ::: "memory");   // same-wave DS in-order

    // ---- finalize my 16 h values (lanes 0-15; others duplicate harmlessly) ----
    float pr = phh[wave][0][fb][fu];
    float pz = phh[wave][1][fb][fu];
    float pn = phh[wave][2][fb][fu];
    float r = sigm(b2f(cr) + br_ + pr);
    float z = sigm(b2f(cz) + bz_ + pz);
    float n = tanh_fast(b2f(cn) + bn_ + r * pn);
    float h = (1.f - z) * n + z * hprev;
    hprev = h;
    unsigned int hu = f2b(h);
    cr = nr_; cz = nz_; cn = nn_;

    // ---- publish: lanes 0-3 own packet (batch b = lane) ----
    int b = lane & 3;
    unsigned int u0v = (unsigned int)__shfl((int)hu, 0 + b);
    unsigned int u1v = (unsigned int)__shfl((int)hu, 4 + b);
    unsigned int u2v = (unsigned int)__shfl((int)hu, 8 + b);
    unsigned int u3v = (unsigned int)__shfl((int)hu, 12 + b);
    if (lane < 4) {
      u32x4 pkt;
      pkt.x = (u0v & 0xffffu) | (u1v << 16);
      pkt.y = (u2v & 0xffffu) | (u3v << 16);
      pkt.z = (unsigned int)(t + 1);
      pkt.w = 0u;
      unsigned long long sa = (((t + 1) & 1) ? base1 : base0)
                            + (unsigned long long)((b * 224 + G) << 4);
      asm volatile("global_store_dwordx4 %0, %1, off sc0 sc1"
                   :: "v"(sa), "v"(pkt) : "memory");
      *(uint2*)(O32 + (size_t)(t * 4 + b) * 448 + G * 2) = make_uint2(pkt.x, pkt.y);
    }
  }
}

// ---------------- NLL: per-block reduction, NO atomics ----------------
__global__ __launch_bounds__(256) void k_nll(
    const float* __restrict__ logits, const float* __restrict__ y,
    float* __restrict__ partials)
{
  __shared__ float ps[4];
  int wid = threadIdx.x >> 6, lane = threadIdx.x & 63;
  int row = blockIdx.x * 4 + wid;
  const float* lr = logits + (size_t)row * 256;
  float v0 = lr[lane], v1 = lr[lane + 64], v2 = lr[lane + 128], v3 = lr[lane + 192];
  float mx = fmaxf(fmaxf(v0, v1), fmaxf(v2, v3));
  for (int off = 32; off > 0; off >>= 1) mx = fmaxf(mx, __shfl_xor(mx, off));
  float se = __expf(v0 - mx) + __expf(v1 - mx) + __expf(v2 - mx) + __expf(v3 - mx);
  for (int off = 32; off > 0; off >>= 1) se += __shfl_xor(se, off);
  if (lane == 0) {
    float w = y[row];
    int q = (int)floorf((w + 1.f) * 128.f);
    q = q < 0 ? 0 : (q > 255 ? 255 : q);
    ps[wid] = (logf(se) + mx) - lr[q];
  }
  __syncthreads();
  if (threadIdx.x == 0) partials[blockIdx.x] = ps[0] + ps[1] + ps[2] + ps[3];
}

__global__ __launch_bounds__(256) void k_final(const float* __restrict__ partials,
                                               float* __restrict__ out)
{
  __shared__ float s[4];
  int tid = threadIdx.x;
  float a = 0.f;
  for (int i = tid; i < 2560; i += 256) a += partials[i];
  for (int off = 32; off > 0; off >>= 1) a += __shfl_xor(a, off);
  if ((tid & 63) == 0) s[tid >> 6] = a;
  __syncthreads();
  if (tid == 0) out[0] = (s[0] + s[1] + s[2] + s[3]) * (1.f / 10240.f);
}

// ---------------- host ----------------
extern "C" void kernel_launch(void* const* d_in, const int* in_sizes, int n_in,
                              void* d_out, int out_size, void* d_ws, size_t ws_size,
                              hipStream_t stream)
{
  const float* x       = (const float*)d_in[0];
  const float* y       = (const float*)d_in[1];
  const float* m0f_Wih = (const float*)d_in[2];
  const float* m0f_Whh = (const float*)d_in[3];
  const float* m0f_bih = (const float*)d_in[4];
  const float* m0f_bhh = (const float*)d_in[5];
  const float* m0b_Wih = (const float*)d_in[6];
  const float* m0b_Whh = (const float*)d_in[7];
  const float* m0b_bih = (const float*)d_in[8];
  const float* m0b_bhh = (const float*)d_in[9];
  const float* m1f_Wih = (const float*)d_in[10];
  const float* m1f_Whh = (const float*)d_in[11];
  const float* m1f_bih = (const float*)d_in[12];
  const float* m1f_bhh = (const float*)d_in[13];
  const float* m1b_Wih = (const float*)d_in[14];
  const float* m1b_Whh = (const float*)d_in[15];
  const float* m1b_bih = (const float*)d_in[16];
  const float* m1b_bhh = (const float*)d_in[17];
  const float* w_Wih   = (const float*)d_in[18];
  const float* w_Whh   = (const float*)d_in[19];
  const float* w_bih   = (const float*)d_in[20];
  const float* w_bhh   = (const float*)d_in[21];
  const float* Wp      = (const float*)d_in[22];
  const float* bp      = (const float*)d_in[23];
  const float* E       = (const float*)d_in[24];
  const float* Wd      = (const float*)d_in[25];
  const float* bd      = (const float*)d_in[26];

  char* ws = (char*)d_ws;
  size_t off = 0;
  auto alloc = [&](size_t bytes) -> void* {
    void* p = ws + off;
    off += (bytes + 255) & ~(size_t)255;
    return p;
  };
  // misc (zeroed each launch): h packet buffers
  unsigned int* hslots = (unsigned int*)alloc(2 * 896 * 16);
  size_t misc_bytes = off;

  float* c0   = (float*)alloc((size_t)32 * 4 * 256 * 4);
  float* c1   = (float*)alloc((size_t)32 * 4 * 256 * 4);
  float* gi0f = (float*)alloc((size_t)32 * 4 * 384 * 4);
  float* gi0b = (float*)alloc((size_t)32 * 4 * 384 * 4);
  float* gi1f = (float*)alloc((size_t)32 * 4 * 384 * 4);
  float* gi1b = (float*)alloc((size_t)32 * 4 * 384 * 4);
  unsigned short* Eb    = (unsigned short*)alloc((size_t)256 * 256 * 2);
  unsigned short* c1b   = (unsigned short*)alloc((size_t)32 * 4 * 256 * 2);
  unsigned short* gpack = (unsigned short*)alloc((size_t)2560 * 224 * 48 * 2);
  unsigned int*   O32   = (unsigned int*)alloc((size_t)10240 * 448 * 4);
  unsigned short* O2    = (unsigned short*)alloc((size_t)10240 * 512 * 2);
  float*          LG    = (float*)alloc((size_t)10240 * 256 * 4);
  float*          PT    = (float*)alloc((size_t)2560 * 4);
  unsigned short* Wih_b = (unsigned short*)alloc((size_t)2688 * 512 * 2);
  unsigned short* Whh_p = (unsigned short*)alloc((size_t)224 * 28 * 512 * 2);
  unsigned short* Wp_b  = (unsigned short*)alloc((size_t)512 * 896 * 2);
  unsigned short* Wd_b  = (unsigned short*)alloc((size_t)256 * 512 * 2);

  hipMemsetAsync(d_ws, 0, misc_bytes, stream);

  // fused weight preprocessing (4 casts + Whh swizzle)
  {
    int total = 2688 * 512 + 512 * 896 + 256 * 512 + 256 * 256 + 224 * 28 * 512;
    k_prep<<<(total + 255) / 256, 256, 0, stream>>>(
        w_Wih, Wp, Wd, E, w_Whh, Wih_b, Wp_b, Wd_b, Eb, Whh_p);
  }

  // encoder
  k_gi_enc<<<128, 384, 0, stream>>>(x, m0f_Wih, m0f_bih, gi0f, 80);
  k_gi_enc<<<128, 384, 0, stream>>>(x, m0b_Wih, m0b_bih, gi0b, 80);
  k_scan_enc<<<2, 512, 0, stream>>>(gi0f, gi0b, m0f_Whh, m0f_bhh, m0b_Whh, m0b_bhh,
                                    c0, nullptr);
  k_gi_enc<<<128, 384, 0, stream>>>(c0, m1f_Wih, m1f_bih, gi1f, 256);
  k_gi_enc<<<128, 384, 0, stream>>>(c0, m1b_Wih, m1b_bih, gi1b, 256);
  k_scan_enc<<<2, 512, 0, stream>>>(gi1f, gi1b, m1f_Whh, m1f_bhh, m1b_Whh, m1b_bhh,
                                    c1, c1b);

  // gi GEMM: A fused from Eb/c1b/y, output written packed (includes bih)
  k_mgemm<<<dim3(80, 21), 256, 0, stream>>>(nullptr, Wih_b, w_bih, (void*)gpack,
                                            10240, 2688, 512, 0, 1, 1, 1, Eb, c1b, y);

  // recurrent wav GRU (persistent, tag-based LLC sync; sparse re-poll)
  k_wav_rnn<<<NWG, 256, 0, stream>>>(Whh_p, w_bhh, gpack, hslots, O32);

  // head
  k_mgemm<<<dim3(80, 4), 256, 0, stream>>>((const unsigned short*)O32, Wp_b, bp,
                                           (void*)O2, 10240, 512, 896, 1, 1, 0, 0,
                                           nullptr, nullptr, nullptr);
  k_mgemm<<<dim3(80, 2), 256, 0, stream>>>(O2, Wd_b, bd, (void*)LG,
                                           10240, 256, 512, 0, 0, 0, 0,
                                           nullptr, nullptr, nullptr);
  k_nll<<<2560, 256, 0, stream>>>(LG, y, PT);
  k_final<<<1, 256, 0, stream>>>(PT, (float*)d_out);
}

// Round 6
// 5060.244 us; speedup vs baseline: 1.7752x; 1.0908x over previous
//
#include <hip/hip_runtime.h>
#include <stdint.h>
#include <math.h>

typedef __attribute__((ext_vector_type(8))) short bf16x8;
typedef __attribute__((ext_vector_type(4))) float f32x4;
typedef __attribute__((ext_vector_type(4))) unsigned int u32x4;

#define BATCH 4
#define T_M 32
#define DE 128
#define T_W 2560
#define NWG 56        /* wav-rnn WGs; 4 waves each; wave owns 4 units; 56*4*4 = 896 */

__device__ __forceinline__ float b2f(unsigned short h) {
  return __uint_as_float(((unsigned int)h) << 16);
}
__device__ __forceinline__ unsigned short f2b(float f) {
  unsigned int u = __float_as_uint(f);
  u = u + 0x7fffu + ((u >> 16) & 1u);   // RNE
  return (unsigned short)(u >> 16);
}
__device__ __forceinline__ float blo(unsigned int u){ return __uint_as_float(u << 16); }
__device__ __forceinline__ float bhi(unsigned int u){ return __uint_as_float(u & 0xffff0000u); }
__device__ __forceinline__ float sigm(float x){
  return __builtin_amdgcn_rcpf(1.f + __expf(-x));
}
__device__ __forceinline__ float tanh_fast(float x){
  float x2 = fminf(fmaxf(x + x, -30.f), 30.f);
  return 1.f - 2.f * __builtin_amdgcn_rcpf(__expf(x2) + 1.f);
}
__device__ __forceinline__ float gelu_exact(float x){ return 0.5f * x * (1.f + erff(x * 0.70710678118654752f)); }

// ---------------- fused preprocessing: 4 bf16 casts + Whh swizzle ----------------
__global__ __launch_bounds__(256) void k_prep(
    const float* __restrict__ wih, const float* __restrict__ wp,
    const float* __restrict__ wd, const float* __restrict__ e,
    const float* __restrict__ whh,
    unsigned short* __restrict__ wih_b, unsigned short* __restrict__ wp_b,
    unsigned short* __restrict__ wd_b, unsigned short* __restrict__ eb,
    unsigned short* __restrict__ whh_p)
{
  int idx = blockIdx.x * 256 + threadIdx.x;
  const int N0 = 2688 * 512, N1 = 512 * 896, N2 = 256 * 512, N3 = 256 * 256;
  if (idx < N0) { wih_b[idx] = f2b(wih[idx]); return; }
  idx -= N0;
  if (idx < N1) { wp_b[idx] = f2b(wp[idx]); return; }
  idx -= N1;
  if (idx < N2) { wd_b[idx] = f2b(wd[idx]); return; }
  idx -= N2;
  if (idx < N3) { eb[idx] = f2b(e[idx]); return; }
  idx -= N3;
  if (idx >= 224 * 28 * 512) return;
  int j    = idx & 7;
  int r16  = (idx >> 3) & 15;
  int quad = (idx >> 7) & 3;
  int kc   = (idx >> 9) % 28;
  int G    = (idx >> 9) / 28;
  unsigned short val = 0;
  if (r16 < 12) {
    int row = (r16 >> 2) * 896 + G * 4 + (r16 & 3);
    int col = kc * 32 + quad * 8 + j;
    val = f2b(whh[(size_t)row * 896 + col]);
  }
  whh_p[idx] = val;
}

// ---------------- encoder: input projections gi = in @ Wih^T + bih (float4) ---------
__global__ __launch_bounds__(384) void k_gi_enc(
    const float* __restrict__ in, const float* __restrict__ Wih,
    const float* __restrict__ bih, float* __restrict__ out, int K)
{
  __shared__ float in_s[256];
  int tb = blockIdx.x;
  for (int i = threadIdx.x; i < K; i += 384) in_s[i] = in[tb * K + i];
  __syncthreads();
  int row = threadIdx.x;
  float acc = bih[row];
  const float* wr = Wih + row * K;
  for (int k = 0; k < K; k += 4) {
    float4 w = *(const float4*)(wr + k);
    float4 v = *(const float4*)(in_s + k);
    acc += w.x * v.x + w.y * v.y + w.z * v.z + w.w * v.w;
  }
  out[tb * 384 + row] = acc;
}

// ---------------- encoder: sequential scan, one WG per direction ----------------
// Phase 1: one thread per Whh row (384), computes all 4 batches (no redundant
// Whh re-reads; proven r4, -772us on the non-wav total). FP accumulation order
// per (row,b) identical to baseline.
__global__ __launch_bounds__(512) void k_scan_enc(
    const float* __restrict__ gi_f, const float* __restrict__ gi_b,
    const float* __restrict__ whh_f, const float* __restrict__ bhh_f,
    const float* __restrict__ whh_b, const float* __restrict__ bhh_b,
    float* __restrict__ c_out, unsigned short* __restrict__ cb)   // (32,4,256)
{
  const int dir = blockIdx.x, tid = threadIdx.x;
  const float* gi  = dir ? gi_b  : gi_f;
  const float* whh = dir ? whh_b : whh_f;
  const float* bhh = dir ? bhh_b : bhh_f;
  __shared__ unsigned short h_s[BATCH][DE + 8];
  __shared__ float gh_s[384][4];
  __shared__ float bhh_s[384];
  for (int i = tid; i < 384; i += 512) bhh_s[i] = bhh[i];
  for (int i = tid; i < BATCH * (DE + 8); i += 512) ((unsigned short*)h_s)[i] = 0;
  __syncthreads();
  for (int s = 0; s < T_M; ++s) {
    int t = dir ? (T_M - 1 - s) : s;
    if (tid < 384) {
      const float* wr = whh + tid * DE;
      float a0 = 0.f, a1 = 0.f, a2 = 0.f, a3 = 0.f;
      for (int j = 0; j < DE; j += 8) {
        float4 w0 = *(const float4*)(wr + j);
        float4 w1 = *(const float4*)(wr + j + 4);
        uint4 h0 = *(const uint4*)&h_s[0][j];
        uint4 h1 = *(const uint4*)&h_s[1][j];
        uint4 h2 = *(const uint4*)&h_s[2][j];
        uint4 h3 = *(const uint4*)&h_s[3][j];
        a0 += w0.x * blo(h0.x) + w0.y * bhi(h0.x) + w0.z * blo(h0.y) + w0.w * bhi(h0.y);
        a0 += w1.x * blo(h0.z) + w1.y * bhi(h0.z) + w1.z * blo(h0.w) + w1.w * bhi(h0.w);
        a1 += w0.x * blo(h1.x) + w0.y * bhi(h1.x) + w0.z * blo(h1.y) + w0.w * bhi(h1.y);
        a1 += w1.x * blo(h1.z) + w1.y * bhi(h1.z) + w1.z * blo(h1.w) + w1.w * bhi(h1.w);
        a2 += w0.x * blo(h2.x) + w0.y * bhi(h2.x) + w0.z * blo(h2.y) + w0.w * bhi(h2.y);
        a2 += w1.x * blo(h2.z) + w1.y * bhi(h2.z) + w1.z * blo(h2.w) + w1.w * bhi(h2.w);
        a3 += w0.x * blo(h3.x) + w0.y * bhi(h3.x) + w0.z * blo(h3.y) + w0.w * bhi(h3.y);
        a3 += w1.x * blo(h3.z) + w1.y * bhi(h3.z) + w1.z * blo(h3.w) + w1.w * bhi(h3.w);
      }
      float bb_ = bhh_s[tid];
      *(float4*)&gh_s[tid][0] = make_float4(a0 + bb_, a1 + bb_, a2 + bb_, a3 + bb_);
    }
    __syncthreads();
    {
      int u = tid >> 2, b = tid & 3;
      const float* git = gi + (t * BATCH + b) * 384;
      float r = sigm(git[u] + gh_s[u][b]);
      float z = sigm(git[DE + u] + gh_s[DE + u][b]);
      float n = tanh_fast(git[2 * DE + u] + r * gh_s[2 * DE + u][b]);
      float hold = b2f(h_s[b][u]);
      float hnew = (1.f - z) * n + z * hold;
      int oi = (t * BATCH + b) * 256 + dir * DE + u;
      c_out[oi] = hnew;
      if (cb) cb[oi] = f2b(hnew);
      h_s[b][u] = f2b(hnew);
    }
    __syncthreads();
  }
}

// ---------------- MFMA GEMM: C(MxN) = act(A(bf16 MxK) @ B(bf16 NxK)^T + bias) -------
__global__ __launch_bounds__(256) void k_mgemm(
    const unsigned short* __restrict__ A, const unsigned short* __restrict__ B,
    const float* __restrict__ bias, void* __restrict__ C,
    int M, int N, int K, int act, int c_bf16, int swz, int afuse,
    const unsigned short* __restrict__ Eb, const unsigned short* __restrict__ c1b,
    const float* __restrict__ yw)
{
  __shared__ unsigned short As[128][40];
  __shared__ unsigned short Bs[128][40];
  const int tid = threadIdx.x;
  const int m0 = blockIdx.x * 128, n0 = blockIdx.y * 128;
  const int lane = tid & 63, wave = tid >> 6;
  const int wy = wave >> 1, wx = wave & 1;
  const int row16 = lane & 15, quad = lane >> 4;
  const int sr = tid >> 1, sc = (tid & 1) * 16;
  const unsigned short* arow0 = nullptr;
  const unsigned short* arow1 = nullptr;
  if (afuse) {
    int row = m0 + sr, tt = row >> 2, b = row & 3;
    float w = (tt == 0) ? 0.f : yw[(tt - 1) * 4 + b];
    int q = (int)floorf((w + 1.f) * 128.f);
    q = q < 0 ? 0 : (q > 255 ? 255 : q);
    arow0 = Eb + q * 256;
    arow1 = c1b + ((tt / 80) * 4 + b) * 256;
  }
  f32x4 acc[4][4] = {};
  for (int kt = 0; kt < K; kt += 32) {
    uint4 av, av2;
    if (afuse) {
      int kk = kt + sc;
      const unsigned short* src = (kk < 256) ? (arow0 + kk) : (arow1 + kk - 256);
      av  = *(const uint4*)src;
      av2 = *(const uint4*)(src + 8);
    } else {
      av  = *(const uint4*)(A + (size_t)(m0 + sr) * K + kt + sc);
      av2 = *(const uint4*)(A + (size_t)(m0 + sr) * K + kt + sc + 8);
    }
    uint4 bv  = *(const uint4*)(B + (size_t)(n0 + sr) * K + kt + sc);
    uint4 bv2 = *(const uint4*)(B + (size_t)(n0 + sr) * K + kt + sc + 8);
    __syncthreads();
    *(uint4*)&As[sr][sc] = av; *(uint4*)&As[sr][sc + 8] = av2;
    *(uint4*)&Bs[sr][sc] = bv; *(uint4*)&Bs[sr][sc + 8] = bv2;
    __syncthreads();
    bf16x8 af[4], bf[4];
    #pragma unroll
    for (int i = 0; i < 4; ++i) af[i] = *(const bf16x8*)&As[wy * 64 + i * 16 + row16][quad * 8];
    #pragma unroll
    for (int j = 0; j < 4; ++j) bf[j] = *(const bf16x8*)&Bs[wx * 64 + j * 16 + row16][quad * 8];
    #pragma unroll
    for (int i = 0; i < 4; ++i)
      #pragma unroll
      for (int j = 0; j < 4; ++j)
        acc[i][j] = __builtin_amdgcn_mfma_f32_16x16x32_bf16(af[i], bf[j], acc[i][j], 0, 0, 0);
  }
  #pragma unroll
  for (int i = 0; i < 4; ++i) {
    #pragma unroll
    for (int j = 0; j < 4; ++j) {
      int col = n0 + wx * 64 + j * 16 + row16;
      float bs = bias[col];
      #pragma unroll
      for (int r = 0; r < 4; ++r) {
        int row = m0 + wy * 64 + i * 16 + quad * 4 + r;
        float v = acc[i][j][r] + bs;
        if (act) v = gelu_exact(v);
        if (swz) {
          int t = row >> 2, b = row & 3;
          int g = col / 896, rem = col - g * 896;
          int G = rem >> 2, u = rem & 3;
          ((unsigned short*)C)[(size_t)(t * 224 + G) * 48 + g * 16 + b * 4 + u] = f2b(v);
        } else if (c_bf16) {
          ((unsigned short*)C)[(size_t)row * N + col] = f2b(v);
        } else {
          ((float*)C)[(size_t)row * N + col] = v;
        }
      }
    }
  }
}

// ---------------- wav GRU: 56 WGs x 4 waves; wave owns G (4 units) ------------------
// Round-0 LLC protocol verbatim (tag-in-packet, double buffer, sc0 sc1, dense
// always-reload poll) — the fastest verified recurrence (4378us). r4's sparse
// re-poll regressed (broke coalescing, FETCH unchanged); r1/r5 multi-domain
// variants hung; r2/r3 single-XCD variants were request-rate bound. This is the
// verified optimum of the protocol family explored.
__global__ __launch_bounds__(256, 1) void k_wav_rnn(
    const unsigned short* __restrict__ whh_p,  // swizzled (224,28,4,16,8) bf16
    const float* __restrict__ bhh,             // (2688,)
    const unsigned short* __restrict__ gp_,    // packed gi (2560,224,3,4,4) bf16
    unsigned int* __restrict__ hslots,         // 2*896 packets of 16B, zeroed
    unsigned int* __restrict__ O32)            // (10240,448) dwords of bf16 pairs
{
  const int wg = blockIdx.x, tid = threadIdx.x;
  const int lane = tid & 63, wave = tid >> 6;
  const int G = wg * 4 + wave;                 // global 4-unit group

  __shared__ unsigned short h_lds[2][4][912];  // h(t) double buffer, stride 1824B
  __shared__ float phh[4][3][4][4];            // [wave][gate][batch][unit]

  const int r16 = lane & 15, quad = lane >> 4, bb = lane & 3;
  const int fu = (lane >> 2) & 3, fb = lane & 3;   // finalize mapping (lanes 0-15 real)

  // ---- Whh fragments -> VGPRs (28 x bf16x8 = 112 VGPRs), coalesced 16B/lane ----
  bf16x8 wf[28];
  {
    const bf16x8* W8 = (const bf16x8*)whh_p + (size_t)G * 28 * 64;
    #pragma unroll
    for (int kc = 0; kc < 28; ++kc)
      wf[kc] = W8[(kc * 4 + quad) * 16 + r16];
  }

  // ---- per-lane bias + recurrent state ----
  const float br_ = bhh[G * 4 + fu];
  const float bz_ = bhh[896 + G * 4 + fu];
  const float bn_ = bhh[1792 + G * 4 + fu];
  float hprev = 0.f;
  const unsigned short* gl0 = gp_ + (size_t)G * 48 + fb * 4 + fu;
  unsigned short cr = gl0[0], cz = gl0[16], cn = gl0[32];   // gi(0), raw bf16 bits

  // ---- poll slice: thread covers packets tid, tid+256, tid+512, (tid+768 | dup) ----
  const int p0 = tid, p1 = tid + 256, p2 = tid + 512;
  const int p3 = (tid < 128) ? tid + 768 : tid;    // dup of own p0 when out of range
  const int pb0 = p0 / 224, pG0 = p0 - pb0 * 224;
  const int pb1 = p1 / 224, pG1 = p1 - pb1 * 224;
  const int pb2 = p2 / 224, pG2 = p2 - pb2 * 224;
  const int pb3 = p3 / 224, pG3 = p3 - pb3 * 224;

  const unsigned long long base0 = (unsigned long long)hslots;
  const unsigned long long base1 = base0 + 14336ull;

  for (int t = 0; t < T_W; ++t) {
    // ---- poll my 4 packets (tags == t) ----
    const unsigned long long hb = (t & 1) ? base1 : base0;
    unsigned long long a0 = hb + ((unsigned long long)p0 << 4);
    unsigned long long a1 = hb + ((unsigned long long)p1 << 4);
    unsigned long long a2 = hb + ((unsigned long long)p2 << 4);
    unsigned long long a3 = hb + ((unsigned long long)p3 << 4);
    u32x4 s0, s1, s2, s3;
    const unsigned int tg = (unsigned int)t;
    for (;;) {
      asm volatile(
        "global_load_dwordx4 %0, %4, off sc0 sc1\n"
        "global_load_dwordx4 %1, %5, off sc0 sc1\n"
        "global_load_dwordx4 %2, %6, off sc0 sc1\n"
        "global_load_dwordx4 %3, %7, off sc0 sc1\n"
        "s_waitcnt vmcnt(0)"
        : "=&v"(s0), "=&v"(s1), "=&v"(s2), "=&v"(s3)
        : "v"(a0), "v"(a1), "v"(a2), "v"(a3)
        : "memory");
      unsigned int bad = (s0.z ^ tg) | (s1.z ^ tg) | (s2.z ^ tg) | (s3.z ^ tg);
      if (!__any(bad != 0)) break;
    }

    // ---- issue gi(t+1) loads now (raw bf16 bits; consumed at next finalize) ----
    int tn = (t + 1 < T_W) ? (t + 1) : t;
    const unsigned short* gp = gp_ + (size_t)tn * 10752 + G * 48 + fb * 4 + fu;
    unsigned short nr_ = gp[0], nz_ = gp[16], nn_ = gp[32];

    // ---- scatter h(t) into LDS buffer t&1 ----
    *(uint2*)&h_lds[t & 1][pb0][pG0 * 4] = make_uint2(s0.x, s0.y);
    *(uint2*)&h_lds[t & 1][pb1][pG1 * 4] = make_uint2(s1.x, s1.y);
    *(uint2*)&h_lds[t & 1][pb2][pG2 * 4] = make_uint2(s2.x, s2.y);
    *(uint2*)&h_lds[t & 1][pb3][pG3 * 4] = make_uint2(s3.x, s3.y);
    __syncthreads();   // single barrier: h(t) fully in LDS

    // ---- 28 MFMAs, 4 interleaved accumulator chains ----
    f32x4 ac0 = {}, ac1 = {}, ac2 = {}, ac3 = {};
    #pragma unroll
    for (int kc = 0; kc < 28; kc += 4) {
      bf16x8 h0 = *(const bf16x8*)&h_lds[t & 1][bb][(kc + 0) * 32 + quad * 8];
      bf16x8 h1 = *(const bf16x8*)&h_lds[t & 1][bb][(kc + 1) * 32 + quad * 8];
      bf16x8 h2 = *(const bf16x8*)&h_lds[t & 1][bb][(kc + 2) * 32 + quad * 8];
      bf16x8 h3 = *(const bf16x8*)&h_lds[t & 1][bb][(kc + 3) * 32 + quad * 8];
      ac0 = __builtin_amdgcn_mfma_f32_16x16x32_bf16(wf[kc + 0], h0, ac0, 0, 0, 0);
      ac1 = __builtin_amdgcn_mfma_f32_16x16x32_bf16(wf[kc + 1], h1, ac1, 0, 0, 0);
      ac2 = __builtin_amdgcn_mfma_f32_16x16x32_bf16(wf[kc + 2], h2, ac2, 0, 0, 0);
      ac3 = __builtin_amdgcn_mfma_f32_16x16x32_bf16(wf[kc + 3], h3, ac3, 0, 0, 0);
    }
    f32x4 ac;
    ac[0] = ac0[0] + ac1[0] + ac2[0] + ac3[0];
    ac[1] = ac0[1] + ac1[1] + ac2[1] + ac3[1];
    ac[2] = ac0[2] + ac1[2] + ac2[2] + ac3[2];
    ac[3] = ac0[3] + ac1[3] + ac2[3] + ac3[3];

    // ---- in-wave transpose via LDS: D[row=quad*4+reg][col=r16] -> phh[v][g][b][u] ----
    if (r16 < 4 && quad < 3)
      *(f32x4*)&phh[wave][quad][r16][0] = ac;
    asm volatile("s_waitcnt lgkmcnt(0)" ::: "memory");   // same-wave DS in-order

    // ---- finalize my 16 h values (lanes 0-15; others duplicate harmlessly) ----
    float pr = phh[wave][0][fb][fu];
    float pz = phh[wave][1][fb][fu];
    float pn = phh[wave][2][fb][fu];
    float r = sigm(b2f(cr) + br_ + pr);
    float z = sigm(b2f(cz) + bz_ + pz);
    float n = tanh_fast(b2f(cn) + bn_ + r * pn);
    float h = (1.f - z) * n + z * hprev;
    hprev = h;
    unsigned int hu = f2b(h);
    cr = nr_; cz = nz_; cn = nn_;

    // ---- publish: lanes 0-3 own packet (batch b = lane) ----
    int b = lane & 3;
    unsigned int u0v = (unsigned int)__shfl((int)hu, 0 + b);
    unsigned int u1v = (unsigned int)__shfl((int)hu, 4 + b);
    unsigned int u2v = (unsigned int)__shfl((int)hu, 8 + b);
    unsigned int u3v = (unsigned int)__shfl((int)hu, 12 + b);
    if (lane < 4) {
      u32x4 pkt;
      pkt.x = (u0v & 0xffffu) | (u1v << 16);
      pkt.y = (u2v & 0xffffu) | (u3v << 16);
      pkt.z = (unsigned int)(t + 1);
      pkt.w = 0u;
      unsigned long long sa = (((t + 1) & 1) ? base1 : base0)
                            + (unsigned long long)((b * 224 + G) << 4);
      asm volatile("global_store_dwordx4 %0, %1, off sc0 sc1"
                   :: "v"(sa), "v"(pkt) : "memory");
      *(uint2*)(O32 + (size_t)(t * 4 + b) * 448 + G * 2) = make_uint2(pkt.x, pkt.y);
    }
  }
}

// ---------------- NLL: per-block reduction, NO atomics ----------------
__global__ __launch_bounds__(256) void k_nll(
    const float* __restrict__ logits, const float* __restrict__ y,
    float* __restrict__ partials)
{
  __shared__ float ps[4];
  int wid = threadIdx.x >> 6, lane = threadIdx.x & 63;
  int row = blockIdx.x * 4 + wid;
  const float* lr = logits + (size_t)row * 256;
  float v0 = lr[lane], v1 = lr[lane + 64], v2 = lr[lane + 128], v3 = lr[lane + 192];
  float mx = fmaxf(fmaxf(v0, v1), fmaxf(v2, v3));
  for (int off = 32; off > 0; off >>= 1) mx = fmaxf(mx, __shfl_xor(mx, off));
  float se = __expf(v0 - mx) + __expf(v1 - mx) + __expf(v2 - mx) + __expf(v3 - mx);
  for (int off = 32; off > 0; off >>= 1) se += __shfl_xor(se, off);
  if (lane == 0) {
    float w = y[row];
    int q = (int)floorf((w + 1.f) * 128.f);
    q = q < 0 ? 0 : (q > 255 ? 255 : q);
    ps[wid] = (logf(se) + mx) - lr[q];
  }
  __syncthreads();
  if (threadIdx.x == 0) partials[blockIdx.x] = ps[0] + ps[1] + ps[2] + ps[3];
}

__global__ __launch_bounds__(256) void k_final(const float* __restrict__ partials,
                                               float* __restrict__ out)
{
  __shared__ float s[4];
  int tid = threadIdx.x;
  float a = 0.f;
  for (int i = tid; i < 2560; i += 256) a += partials[i];
  for (int off = 32; off > 0; off >>= 1) a += __shfl_xor(a, off);
  if ((tid & 63) == 0) s[tid >> 6] = a;
  __syncthreads();
  if (tid == 0) out[0] = (s[0] + s[1] + s[2] + s[3]) * (1.f / 10240.f);
}

// ---------------- host ----------------
extern "C" void kernel_launch(void* const* d_in, const int* in_sizes, int n_in,
                              void* d_out, int out_size, void* d_ws, size_t ws_size,
                              hipStream_t stream)
{
  const float* x       = (const float*)d_in[0];
  const float* y       = (const float*)d_in[1];
  const float* m0f_Wih = (const float*)d_in[2];
  const float* m0f_Whh = (const float*)d_in[3];
  const float* m0f_bih = (const float*)d_in[4];
  const float* m0f_bhh = (const float*)d_in[5];
  const float* m0b_Wih = (const float*)d_in[6];
  const float* m0b_Whh = (const float*)d_in[7];
  const float* m0b_bih = (const float*)d_in[8];
  const float* m0b_bhh = (const float*)d_in[9];
  const float* m1f_Wih = (const float*)d_in[10];
  const float* m1f_Whh = (const float*)d_in[11];
  const float* m1f_bih = (const float*)d_in[12];
  const float* m1f_bhh = (const float*)d_in[13];
  const float* m1b_Wih = (const float*)d_in[14];
  const float* m1b_Whh = (const float*)d_in[15];
  const float* m1b_bih = (const float*)d_in[16];
  const float* m1b_bhh = (const float*)d_in[17];
  const float* w_Wih   = (const float*)d_in[18];
  const float* w_Whh   = (const float*)d_in[19];
  const float* w_bih   = (const float*)d_in[20];
  const float* w_bhh   = (const float*)d_in[21];
  const float* Wp      = (const float*)d_in[22];
  const float* bp      = (const float*)d_in[23];
  const float* E       = (const float*)d_in[24];
  const float* Wd      = (const float*)d_in[25];
  const float* bd      = (const float*)d_in[26];

  char* ws = (char*)d_ws;
  size_t off = 0;
  auto alloc = [&](size_t bytes) -> void* {
    void* p = ws + off;
    off += (bytes + 255) & ~(size_t)255;
    return p;
  };
  // misc (zeroed each launch): h packet buffers
  unsigned int* hslots = (unsigned int*)alloc(2 * 896 * 16);
  size_t misc_bytes = off;

  float* c0   = (float*)alloc((size_t)32 * 4 * 256 * 4);
  float* c1   = (float*)alloc((size_t)32 * 4 * 256 * 4);
  float* gi0f = (float*)alloc((size_t)32 * 4 * 384 * 4);
  float* gi0b = (float*)alloc((size_t)32 * 4 * 384 * 4);
  float* gi1f = (float*)alloc((size_t)32 * 4 * 384 * 4);
  float* gi1b = (float*)alloc((size_t)32 * 4 * 384 * 4);
  unsigned short* Eb    = (unsigned short*)alloc((size_t)256 * 256 * 2);
  unsigned short* c1b   = (unsigned short*)alloc((size_t)32 * 4 * 256 * 2);
  unsigned short* gpack = (unsigned short*)alloc((size_t)2560 * 224 * 48 * 2);
  unsigned int*   O32   = (unsigned int*)alloc((size_t)10240 * 448 * 4);
  unsigned short* O2    = (unsigned short*)alloc((size_t)10240 * 512 * 2);
  float*          LG    = (float*)alloc((size_t)10240 * 256 * 4);
  float*          PT    = (float*)alloc((size_t)2560 * 4);
  unsigned short* Wih_b = (unsigned short*)alloc((size_t)2688 * 512 * 2);
  unsigned short* Whh_p = (unsigned short*)alloc((size_t)224 * 28 * 512 * 2);
  unsigned short* Wp_b  = (unsigned short*)alloc((size_t)512 * 896 * 2);
  unsigned short* Wd_b  = (unsigned short*)alloc((size_t)256 * 512 * 2);

  hipMemsetAsync(d_ws, 0, misc_bytes, stream);

  // fused weight preprocessing (4 casts + Whh swizzle)
  {
    int total = 2688 * 512 + 512 * 896 + 256 * 512 + 256 * 256 + 224 * 28 * 512;
    k_prep<<<(total + 255) / 256, 256, 0, stream>>>(
        w_Wih, Wp, Wd, E, w_Whh, Wih_b, Wp_b, Wd_b, Eb, Whh_p);
  }

  // encoder
  k_gi_enc<<<128, 384, 0, stream>>>(x, m0f_Wih, m0f_bih, gi0f, 80);
  k_gi_enc<<<128, 384, 0, stream>>>(x, m0b_Wih, m0b_bih, gi0b, 80);
  k_scan_enc<<<2, 512, 0, stream>>>(gi0f, gi0b, m0f_Whh, m0f_bhh, m0b_Whh, m0b_bhh,
                                    c0, nullptr);
  k_gi_enc<<<128, 384, 0, stream>>>(c0, m1f_Wih, m1f_bih, gi1f, 256);
  k_gi_enc<<<128, 384, 0, stream>>>(c0, m1b_Wih, m1b_bih, gi1b, 256);
  k_scan_enc<<<2, 512, 0, stream>>>(gi1f, gi1b, m1f_Whh, m1f_bhh, m1b_Whh, m1b_bhh,
                                    c1, c1b);

  // gi GEMM: A fused from Eb/c1b/y, output written packed (includes bih)
  k_mgemm<<<dim3(80, 21), 256, 0, stream>>>(nullptr, Wih_b, w_bih, (void*)gpack,
                                            10240, 2688, 512, 0, 1, 1, 1, Eb, c1b, y);

  // recurrent wav GRU (persistent, tag-based LLC sync; r0 dense poll)
  k_wav_rnn<<<NWG, 256, 0, stream>>>(Whh_p, w_bhh, gpack, hslots, O32);

  // head
  k_mgemm<<<dim3(80, 4), 256, 0, stream>>>((const unsigned short*)O32, Wp_b, bp,
                                           (void*)O2, 10240, 512, 896, 1, 1, 0, 0,
                                           nullptr, nullptr, nullptr);
  k_mgemm<<<dim3(80, 2), 256, 0, stream>>>(O2, Wd_b, bd, (void*)LG,
                                           10240, 256, 512, 0, 0, 0, 0,
                                           nullptr, nullptr, nullptr);
  k_nll<<<2560, 256, 0, stream>>>(LG, y, PT);
  k_final<<<1, 256, 0, stream>>>(PT, (float*)d_out);
}